// Round 3
// baseline (908.355 us; speedup 1.0000x reference)
//
#include <hip/hip_runtime.h>
#include <hip/hip_bf16.h>
#include <math.h>

// GPT3 block on MI355X, round 8:
//  - gemm256d_bt v2: 256x256 tile, 4-deep half-tile ring + PHASE READ-AHEAD.
//    Each phase issues next phase's ds_reads, waits counted lgkmcnt(N) for the
//    PREVIOUS phase's reads, sched_barrier(0), then 16 MFMA -> LDS pipe and
//    matrix pipe overlap (round-7 ran them serially: 7275 cyc/K-tile vs the
//    2064-cyc MFMA floor). Gates: uniform vmcnt(8) at p0/p1/p3, 5-phase cover.
//    3 barriers/K-tile. bv0 double-set (parity) for the p3 read-ahead wrap.
//  - FFB: split-K=4 into fp32 partials + fused reduce4 (no atomics).
//  - Z-projection keeps the 128^2 m97 kernel; attention unchanged.
// ws 144 MiB: bI bWQ bWK bWV | bQ bK bVT bAV bZ bWZT | bWFFAT bWFFBT
// bFFA aliases [0,32MiB). FFB partials alias [32,96MiB) (dead by then).

typedef __bf16 bf16_t;
typedef __bf16 bf16x8 __attribute__((ext_vector_type(8)));
typedef float  f32x4  __attribute__((ext_vector_type(4)));

#define AS1 __attribute__((address_space(1)))
#define AS3 __attribute__((address_space(3)))

__device__ __forceinline__ void load16_lds(const bf16_t* g, bf16_t* l) {
    // 16B per lane, LDS dest = wave-uniform base + lane*16
    __builtin_amdgcn_global_load_lds((AS1 void*)g, (AS3 void*)l, 16, 0, 0);
}

// ---- half-tile staging (ring slot = 128 rows x 64 cols, 16KB) ----
// A half h = logical rows {r : (r>>6)&1 == h} (bit6 partition)
// B half h = logical rows {r : (r>>5)&1 == h} (bit5 partition)
// chunk c of phys row p holds logical chunk c ^ (p&7)  (read-side XOR swizzle)
__device__ __forceinline__ void stageA_half(const bf16_t* __restrict__ Ab, int lda,
                                            int k0, int h, bf16_t* slot,
                                            int w, int lane)
{
    #pragma unroll
    for (int j = 0; j < 2; ++j) {
        const int prw = j * 64 + w * 8;          // wave-uniform phys row base
        const int p   = prw + (lane >> 3);
        const int lr  = (p >> 6) * 128 + h * 64 + (p & 63);
        const int lc  = (lane & 7) ^ (p & 7);
        load16_lds(Ab + (long long)lr * lda + k0 + lc * 8, slot + prw * 64);
    }
}
__device__ __forceinline__ void stageB_half(const bf16_t* __restrict__ Bb, int ldb,
                                            int k0, int h, bf16_t* slot,
                                            int w, int lane)
{
    #pragma unroll
    for (int j = 0; j < 2; ++j) {
        const int prw = j * 64 + w * 8;
        const int p   = prw + (lane >> 3);
        const int lr  = (p >> 5) * 64 + h * 32 + (p & 31);
        const int lc  = (lane & 7) ^ (p & 7);
        load16_lds(Bb + (long long)lr * ldb + k0 + lc * 8, slot + prw * 64);
    }
}

#define LOADAF(DST, SL)                                                        \
  _Pragma("unroll") for (int ks = 0; ks < 2; ++ks)                             \
  _Pragma("unroll") for (int mi = 0; mi < 4; ++mi)                             \
      DST[ks][mi] = *(const bf16x8*)&(SL)[(wm * 64 + mi * 16 + c15) * 64 +     \
                      (((ks * 4 + q4) ^ (c15 & 7)) * 8)];

#define LOADBV(DST, SL)                                                        \
  _Pragma("unroll") for (int ks = 0; ks < 2; ++ks)                             \
  _Pragma("unroll") for (int nj = 0; nj < 2; ++nj)                             \
      DST[ks][nj] = *(const bf16x8*)&(SL)[(wn * 32 + nj * 16 + c15) * 64 +     \
                      (((ks * 4 + q4) ^ (c15 & 7)) * 8)];

#define MFMA8(R0, C0, AF, BV)                                                  \
  _Pragma("unroll") for (int ks = 0; ks < 2; ++ks)                             \
  _Pragma("unroll") for (int mi = 0; mi < 4; ++mi)                             \
  _Pragma("unroll") for (int nj = 0; nj < 2; ++nj)                             \
      acc[(R0) + mi][(C0) + nj] = __builtin_amdgcn_mfma_f32_16x16x32_bf16(     \
          AF[ks][mi], BV[ks][nj], acc[(R0) + mi][(C0) + nj], 0, 0, 0);

#define VMW(N)  asm volatile("s_waitcnt vmcnt(" #N ")" ::: "memory")
#define LGKM(N) asm volatile("s_waitcnt lgkmcnt(" #N ")" ::: "memory")
#define SB()    __builtin_amdgcn_sched_barrier(0)
#define BAR()   __builtin_amdgcn_s_barrier()
#define PRIO1   __builtin_amdgcn_s_setprio(1)
#define PRIO0   __builtin_amdgcn_s_setprio(0)

// Phase structure per K-tile u (P = u&1, Q = 1-P):
//  p0: VMW(8) BAR | stage A1(u+1)->As[2Q+1] | read bv1(u)    | LGKM(4)  | MFMA (0,0) af0*bv0
//  p1: VMW(8) BAR |                          read af1(u)     | LGKM(8)  | MFMA (0,1) af0*bv1
//  p2:            | stage A0,B0(u+2)->As/Bs[2P]              | LGKM(0)  | MFMA (1,1) af1*bv1
//  p3: VMW(8) BAR | stage B1(u+2)->Bs[2P+1] | read af0,bv0(u+1) from [2Q] | MFMA (1,0) af1*bv0
// vmcnt ledger (2 loads per half): every gate completes exactly the 2 or 4
// oldest loads = the half(s) read this phase; issue-to-gate = 5 phases.
#define PH0(P, Q, BV0, KA1)                                                    \
  VMW(8); BAR();                                                               \
  stageA_half(Ab, lda, (KA1), 1, As[2 * (Q) + 1], w, lane);                    \
  LOADBV(bv1, Bs[2 * (P) + 1]);                                                \
  LGKM(4); SB();                                                               \
  PRIO1; MFMA8(0, 0, af0, BV0); PRIO0;

#define PH1(P)                                                                 \
  VMW(8); BAR();                                                               \
  LOADAF(af1, As[2 * (P) + 1]);                                                \
  LGKM(8); SB();                                                               \
  PRIO1; MFMA8(0, 2, af0, bv1); PRIO0;

#define PH2(P, KN2)                                                            \
  stageA_half(Ab, lda, (KN2), 0, As[2 * (P)], w, lane);                        \
  stageB_half(Bb, ldb, (KN2), 0, Bs[2 * (P)], w, lane);                        \
  LGKM(0); SB();                                                               \
  PRIO1; MFMA8(4, 2, af1, bv1); PRIO0;

#define PH3(P, Q, BV0, BV0N, KN2, DOREAD)                                      \
  VMW(8); BAR();                                                               \
  stageB_half(Bb, ldb, (KN2), 1, Bs[2 * (P) + 1], w, lane);                    \
  if constexpr (DOREAD) { LOADAF(af0, As[2 * (Q)]); LOADBV(BV0N, Bs[2 * (Q)]); } \
  SB();                                                                        \
  PRIO1; MFMA8(4, 0, af1, BV0); PRIO0;

#define KTILE(P, Q, BV0, BV0N, KA1, KN2, DOREAD)                               \
  PH0(P, Q, BV0, KA1)                                                          \
  PH1(P)                                                                       \
  PH2(P, KN2)                                                                  \
  PH3(P, Q, BV0, BV0N, KN2, DOREAD)

// ---------------- 256x256 deep-ring GEMM, read-ahead version ----------------
// C = A * B^T: A [M,K] lda, B [N,K] ldb, C [M,N] ldc. 512 thr = 8 waves
// (2M x 4N), per-wave C 128x64, BK=64 in A/B halves. Requires NT even, >=4.
template<typename TOUT>
__global__ __launch_bounds__(512, 2)
void gemm256d_bt(const bf16_t* __restrict__ A, const bf16_t* __restrict__ B,
                 TOUT* __restrict__ Cc, int Kdim,
                 int lda, int ldb, int ldc,
                 long long ab, long long bb, long long cb,
                 int ct_z, bf16_t* __restrict__ ctc, int ldct)
{
    __shared__ __attribute__((aligned(16))) bf16_t As[4][128 * 64];
    __shared__ __attribute__((aligned(16))) bf16_t Bs[4][128 * 64];

    const int z = blockIdx.z;
    A  += (long long)z * ab;
    B  += (long long)z * bb;
    Cc += (long long)z * cb;

    const int bm = blockIdx.y * 256;
    const int bn = blockIdx.x * 256;
    const int t = threadIdx.x, lane = t & 63, w = t >> 6;
    const int wm = w >> 2, wn = w & 3;
    const int q4 = lane >> 4, c15 = lane & 15;

    const bf16_t* Ab = A + (long long)bm * lda;
    const bf16_t* Bb = B + (long long)bn * ldb;

    f32x4  acc[8][4] = {};
    bf16x8 af0[2][4], af1[2][4];    // A sub-half frags (read-ahead af0)
    bf16x8 bv1[2][2];               // B sub-half1 frags
    bf16x8 bv0e[2][2], bv0o[2][2];  // B sub-half0, parity-alternated

    // ---- prologue: stage tile0 (all 4 halves) + tile1 (A0,B0,B1); then
    // wait the 4 oldest (A0,B0 of tile0) and pre-read af0/bv0 of tile 0.
    stageA_half(Ab, lda, 0,  0, As[0], w, lane);
    stageB_half(Bb, ldb, 0,  0, Bs[0], w, lane);
    stageB_half(Bb, ldb, 0,  1, Bs[1], w, lane);
    stageA_half(Ab, lda, 0,  1, As[1], w, lane);
    stageA_half(Ab, lda, 64, 0, As[2], w, lane);
    stageB_half(Bb, ldb, 64, 0, Bs[2], w, lane);
    stageB_half(Bb, ldb, 64, 1, Bs[3], w, lane);
    VMW(10); BAR();
    LOADAF(af0, As[0]);
    LOADBV(bv0e, Bs[0]);

    const int NT = Kdim >> 6;       // even, >= 4

    for (int kt = 0; kt + 3 < NT; kt += 2) {
        const int kA1e = (kt + 1) << 6;
        const int kN2e = (kt + 2) << 6;
        const int kN2o = (kt + 3) << 6;
        KTILE(0, 1, bv0e, bv0o, kA1e, kN2e, 1)
        KTILE(1, 0, bv0o, bv0e, kN2e, kN2o, 1)
    }
    {   // tail pair NT-2 (even), NT-1: out-of-range stages clamp to the last
        // K-tile and land in slots whose data is already consumed (dead).
        const int KD = (NT - 1) << 6;
        KTILE(0, 1, bv0e, bv0o, KD, KD, 1)
        KTILE(1, 0, bv0o, bv0e, KD, KD, 0)
    }

    // ---- epilogue. C/D layout: col = lane&15, row = (lane>>4)*4 + reg ----
    const int rb = q4 * 4;
    if (z == ct_z) {
        // write C^T[n][m] as bf16; 4 consecutive m -> one 8B store
        #pragma unroll
        for (int mi = 0; mi < 8; ++mi) {
            const long long mb = bm + wm * 128 + mi * 16 + rb;
            #pragma unroll
            for (int nj = 0; nj < 4; ++nj) {
                const long long n = bn + wn * 64 + nj * 16 + c15;
                union { bf16_t b[4]; unsigned long long u; } o;
                #pragma unroll
                for (int r = 0; r < 4; ++r) o.b[r] = (bf16_t)acc[mi][nj][r];
                *(unsigned long long*)(ctc + n * ldct + mb) = o.u;
            }
        }
    } else {
        #pragma unroll
        for (int mi = 0; mi < 8; ++mi) {
            #pragma unroll
            for (int r = 0; r < 4; ++r) {
                const long long m = bm + wm * 128 + mi * 16 + rb + r;
                TOUT* crow = Cc + m * ldc + bn + wn * 64 + c15;
                #pragma unroll
                for (int nj = 0; nj < 4; ++nj)
                    crow[nj * 16] = (TOUT)acc[mi][nj][r];
            }
        }
    }
}

// ---------------- GEMM (m97 structure, kept for the 64-tile Z-proj) --------
template<typename TOUT, bool ATOMIC>
__global__ __launch_bounds__(256)
void gemm_bt(const bf16_t* __restrict__ A, const bf16_t* __restrict__ B,
             TOUT* __restrict__ Cc, int Mdim, int Ndim, int Kdim,
             int lda, int ldb, int ldc,
             long long ab, long long bb, long long cb,
             int ct_z, bf16_t* __restrict__ ctc, int ldct)
{
    __shared__ bf16_t Ash[128 * 32];
    __shared__ bf16_t Bsh[128 * 32];

    const int z = blockIdx.z;
    A  += (long long)z * ab;
    B  += (long long)z * bb;
    Cc += (long long)z * cb;

    const int bm = blockIdx.y * 128;
    const int bn = blockIdx.x * 128;
    const int t  = threadIdx.x;
    const int lane = t & 63;
    const int w    = t >> 6;

    const int wm = (w & 1) * 64;
    const int wn = (w >> 1) * 64;

    const int sub = lane >> 2;
    const int seg = lane & 3;

    const bf16_t* Ag0 = A + (long long)(bm + w * 32 + sub) * lda + seg * 8;
    const bf16_t* Ag1 = Ag0 + 16LL * lda;
    const bf16_t* Bg0 = B + (long long)(bn + w * 32 + sub) * ldb + seg * 8;
    const bf16_t* Bg1 = Bg0 + 16LL * ldb;

    bf16_t* Al0 = &Ash[(w * 2 + 0) * 512];
    bf16_t* Al1 = &Ash[(w * 2 + 1) * 512];
    bf16_t* Bl0 = &Bsh[(w * 2 + 0) * 512];
    bf16_t* Bl1 = &Bsh[(w * 2 + 1) * 512];

    const int col  = lane & 15;
    const int koff = (lane >> 4) * 8;

    f32x4 acc[4][4] = {};

    for (int k0 = 0; k0 < Kdim; k0 += 32) {
        load16_lds(Ag0 + k0, Al0);
        load16_lds(Ag1 + k0, Al1);
        load16_lds(Bg0 + k0, Bl0);
        load16_lds(Bg1 + k0, Bl1);
        __syncthreads();

        bf16x8 afr[4], bfr[4];
        #pragma unroll
        for (int mi = 0; mi < 4; ++mi)
            afr[mi] = *(const bf16x8*)&Ash[(wm + mi * 16 + col) * 32 + koff];
        #pragma unroll
        for (int nj = 0; nj < 4; ++nj)
            bfr[nj] = *(const bf16x8*)&Bsh[(wn + nj * 16 + col) * 32 + koff];
        #pragma unroll
        for (int mi = 0; mi < 4; ++mi)
            #pragma unroll
            for (int nj = 0; nj < 4; ++nj)
                acc[mi][nj] = __builtin_amdgcn_mfma_f32_16x16x32_bf16(
                    afr[mi], bfr[nj], acc[mi][nj], 0, 0, 0);
        __syncthreads();
    }

    const int rbase = (lane >> 4) * 4;
    if (z == ct_z) {
        #pragma unroll
        for (int mi = 0; mi < 4; ++mi) {
            const long long mb = bm + wm + mi * 16 + rbase;
            #pragma unroll
            for (int nj = 0; nj < 4; ++nj) {
                const long long n = bn + wn + nj * 16 + col;
                union { bf16_t b[4]; unsigned long long u; } o;
                #pragma unroll
                for (int r = 0; r < 4; ++r) o.b[r] = (bf16_t)acc[mi][nj][r];
                *(unsigned long long*)(ctc + n * ldct + mb) = o.u;
            }
        }
    } else {
        #pragma unroll
        for (int mi = 0; mi < 4; ++mi) {
            #pragma unroll
            for (int r = 0; r < 4; ++r) {
                long long m = bm + wm + mi * 16 + rbase + r;
                TOUT* crow = Cc + m * ldc + bn + wn + col;
                #pragma unroll
                for (int nj = 0; nj < 4; ++nj) {
                    if constexpr (ATOMIC)
                        atomicAdd(&crow[nj * 16], (float)acc[mi][nj][r]);
                    else
                        crow[nj * 16] = (TOUT)acc[mi][nj][r];
                }
            }
        }
    }
}

// ---------------- flash attention ----------------
// Grid (M/64, H). Block 256 = 4 waves; wave owns 16 q-rows. KV tile = 64.
__global__ __launch_bounds__(256, 2)
void flash_attn(const bf16_t* __restrict__ Q, const bf16_t* __restrict__ K,
                const bf16_t* __restrict__ VT, bf16_t* __restrict__ O,
                int M, int D)
{
    __shared__ bf16_t Kt[64 * 128];
    __shared__ bf16_t Vt[128 * 64];
    __shared__ bf16_t Pl[4 * 16 * 88];

    const int t = threadIdx.x, lane = t & 63, w = t >> 6;
    const int q4 = lane >> 4;
    const int c  = lane & 15;
    const int bm = blockIdx.x * 64;
    const int hE = blockIdx.y * 128;

    bf16x8 af_q[4];
    {
        const bf16_t* qrow = Q + (long long)(bm + w * 16 + c) * D + hE + q4 * 8;
        #pragma unroll
        for (int ks = 0; ks < 4; ++ks)
            af_q[ks] = *(const bf16x8*)(qrow + ks * 32);
    }

    f32x4 acc_o[8] = {};
    float m_i[4] = {-INFINITY, -INFINITY, -INFINITY, -INFINITY};
    float l_i[4] = {0.f, 0.f, 0.f, 0.f};

    bf16_t* Pw = &Pl[w * 16 * 88];

    for (int p0 = 0; p0 < M; p0 += 64) {
        #pragma unroll
        for (int j = 0; j < 4; ++j) {
            int krow = w * 16 + j * 4;
            load16_lds(K + (long long)(p0 + krow + q4) * D + hE + ((c ^ (j * 4 + q4)) * 8),
                       &Kt[krow * 128]);
            int vrow = w * 32 + j * 8;
            load16_lds(VT + (long long)(hE + vrow + (lane >> 3)) * M + p0
                          + (((lane & 7) ^ (lane >> 3)) * 8),
                       &Vt[vrow * 64]);
        }
        __syncthreads();

        f32x4 acc_s[4] = {};
        #pragma unroll
        for (int ks = 0; ks < 4; ++ks) {
            #pragma unroll
            for (int nj = 0; nj < 4; ++nj) {
                int row = nj * 16 + c;
                bf16x8 bk = *(const bf16x8*)&Kt[row * 128 + (((ks * 4 + q4) ^ c) * 8)];
                acc_s[nj] = __builtin_amdgcn_mfma_f32_16x16x32_bf16(
                    af_q[ks], bk, acc_s[nj], 0, 0, 0);
            }
        }

        float mt[4], alpha[4], rs[4];
        #pragma unroll
        for (int r = 0; r < 4; ++r) {
            float v = fmaxf(fmaxf(acc_s[0][r], acc_s[1][r]),
                            fmaxf(acc_s[2][r], acc_s[3][r]));
            #pragma unroll
            for (int off = 1; off < 16; off <<= 1)
                v = fmaxf(v, __shfl_xor(v, off));
            mt[r] = v;
        }
        #pragma unroll
        for (int r = 0; r < 4; ++r) {
            float mn = fmaxf(m_i[r], mt[r]);
            alpha[r] = __expf(m_i[r] - mn);
            m_i[r] = mn;
            rs[r] = 0.f;
        }
        #pragma unroll
        for (int nj = 0; nj < 4; ++nj)
            #pragma unroll
            for (int r = 0; r < 4; ++r) {
                float p = __expf(acc_s[nj][r] - m_i[r]);
                rs[r] += p;
                Pw[(q4 * 4 + r) * 88 + nj * 16 + c] = (bf16_t)p;
            }
        #pragma unroll
        for (int r = 0; r < 4; ++r) {
            float v = rs[r];
            #pragma unroll
            for (int off = 1; off < 16; off <<= 1)
                v += __shfl_xor(v, off);
            l_i[r] = alpha[r] * l_i[r] + v;
        }
        #pragma unroll
        for (int nj = 0; nj < 8; ++nj)
            #pragma unroll
            for (int r = 0; r < 4; ++r)
                acc_o[nj][r] *= alpha[r];
        __syncthreads();

        #pragma unroll
        for (int ks = 0; ks < 2; ++ks) {
            bf16x8 ap = *(const bf16x8*)&Pw[c * 88 + ks * 32 + q4 * 8];
            #pragma unroll
            for (int nj = 0; nj < 8; ++nj) {
                int row = nj * 16 + c;
                bf16x8 bvv = *(const bf16x8*)&Vt[row * 64 + (((ks * 4 + q4) ^ (c & 7)) * 8)];
                acc_o[nj] = __builtin_amdgcn_mfma_f32_16x16x32_bf16(
                    ap, bvv, acc_o[nj], 0, 0, 0);
            }
        }
        __syncthreads();
    }

    float inv[4];
    #pragma unroll
    for (int r = 0; r < 4; ++r) inv[r] = 1.0f / l_i[r];
    #pragma unroll
    for (int nj = 0; nj < 8; ++nj)
        #pragma unroll
        for (int r = 0; r < 4; ++r)
            O[(long long)(bm + w * 16 + q4 * 4 + r) * D + hE + nj * 16 + c] =
                (bf16_t)(acc_o[nj][r] * inv[r]);
}

// ---------------- small utility kernels ----------------
__global__ __launch_bounds__(256)
void cast4_bf16(const float* __restrict__ s0, const float* __restrict__ s1,
                const float* __restrict__ s2, const float* __restrict__ s3,
                bf16_t* __restrict__ d0, long long seg, long long n)
{
    const float* src = (blockIdx.y == 0) ? s0 : (blockIdx.y == 1) ? s1
                     : (blockIdx.y == 2) ? s2 : s3;
    bf16_t* dst = d0 + (long long)blockIdx.y * seg;
    long long i = ((long long)blockIdx.x * 256 + threadIdx.x) * 4;
    if (i >= n) return;
    float4 v = *(const float4*)(src + i);
    union { bf16_t b[4]; unsigned long long u; } o;
    o.b[0] = (bf16_t)v.x; o.b[1] = (bf16_t)v.y;
    o.b[2] = (bf16_t)v.z; o.b[3] = (bf16_t)v.w;
    *(unsigned long long*)(dst + i) = o.u;
}

__global__ __launch_bounds__(256)
void transpose_to_bf16(const float* __restrict__ in, bf16_t* __restrict__ out,
                       int rows, int cols)
{
    __shared__ bf16_t tile[32][33];
    const int r0 = blockIdx.y * 32, c0 = blockIdx.x * 32;
    const int tx = threadIdx.x & 31, ty = threadIdx.x >> 5;
    #pragma unroll
    for (int i = 0; i < 4; ++i) {
        int r = ty + i * 8;
        tile[r][tx] = (bf16_t)in[(long long)(r0 + r) * cols + c0 + tx];
    }
    __syncthreads();
    #pragma unroll
    for (int i = 0; i < 4; ++i) {
        int r = ty + i * 8;
        out[(long long)(c0 + r) * rows + r0 + tx] = tile[tx][r];
    }
}

__global__ __launch_bounds__(256)
void reduce4_f32(const float* __restrict__ p, float* __restrict__ out,
                 long long n)
{
    long long i = ((long long)blockIdx.x * 256 + threadIdx.x) * 4;
    if (i >= n) return;
    float4 a = *(const float4*)(p + i);
    float4 b = *(const float4*)(p + n + i);
    float4 c = *(const float4*)(p + 2 * n + i);
    float4 d = *(const float4*)(p + 3 * n + i);
    float4 o;
    o.x = a.x + b.x + c.x + d.x;
    o.y = a.y + b.y + c.y + d.y;
    o.z = a.z + b.z + c.z + d.z;
    o.w = a.w + b.w + c.w + d.w;
    *(float4*)(out + i) = o;
}

extern "C" void kernel_launch(void* const* d_in, const int* in_sizes, int n_in,
                              void* d_out, int out_size, void* d_ws, size_t ws_size,
                              hipStream_t stream)
{
    const float* I    = (const float*)d_in[0];
    const float* WV   = (const float*)d_in[1];
    const float* WK   = (const float*)d_in[2];
    const float* WQ   = (const float*)d_in[3];
    const float* WZ   = (const float*)d_in[4];
    const float* WFFA = (const float*)d_in[5];
    const float* WFFB = (const float*)d_in[6];
    float* out = (float*)d_out;                  // [M, D] fp32

    const int M = 2048, D = 2048, C = 8192;
    const long long MD = (long long)M * D;
    const size_t MiB = 1024 * 1024;

    char* base = (char*)d_ws;
    bf16_t* bI     = (bf16_t*)(base + 0 * MiB);
    bf16_t* bWQ    = (bf16_t*)(base + 8 * MiB);    // contiguous WQ,WK,WV (z-batch)
    bf16_t* bWK    = (bf16_t*)(base + 16 * MiB);
    bf16_t* bWV    = (bf16_t*)(base + 24 * MiB);
    bf16_t* bQ     = (bf16_t*)(base + 32 * MiB);   // contiguous Q,K (z-batch out)
    bf16_t* bK     = (bf16_t*)(base + 40 * MiB);
    bf16_t* bVT    = (bf16_t*)(base + 48 * MiB);   // [D, M] via ct_z epilogue
    bf16_t* bAV    = (bf16_t*)(base + 56 * MiB);
    bf16_t* bZ     = (bf16_t*)(base + 64 * MiB);
    bf16_t* bWZT   = (bf16_t*)(base + 72 * MiB);
    bf16_t* bWFFAT = (bf16_t*)(base + 80 * MiB);   // [C, D]
    bf16_t* bWFFBT = (bf16_t*)(base + 112 * MiB);  // [D, C]
    bf16_t* bFFA   = (bf16_t*)(base + 0 * MiB);    // [M, C] bf16 (bI..bWV dead)
    float*  pF     = (float*)(base + 32 * MiB);    // 4x [M,D] fp32 FFB partials

    const dim3 blk(256);
    const dim3 blk512(512);

    // ---- prep: casts + weight transposes ----
    cast4_bf16<<<dim3(MD / 1024, 4), blk, 0, stream>>>(I, WQ, WK, WV, bI, MD, MD);
    transpose_to_bf16<<<dim3(D / 32, D / 32), blk, 0, stream>>>(WZ,   bWZT,   D, D);
    transpose_to_bf16<<<dim3(C / 32, D / 32), blk, 0, stream>>>(WFFA, bWFFAT, D, C);
    transpose_to_bf16<<<dim3(D / 32, C / 32), blk, 0, stream>>>(WFFB, bWFFBT, C, D);

    // ---- QKV in one z=3 dispatch; V -> bVT transposed ----
    gemm256d_bt<bf16_t><<<dim3(8, 8, 3), blk512, 0, stream>>>(
        bI, bWQ, bQ, D, D, D, D, 0, MD, MD, /*ct_z=*/2, bVT, M);

    // ---- flash attention: Q,K,VT -> AV ----
    flash_attn<<<dim3(M / 64, 16), blk, 0, stream>>>(bQ, bK, bVT, bAV, M, D);

    // ---- Z = AV x WZ^T (64 tiles at 256^2 -> keep 128^2 kernel) ----
    gemm_bt<bf16_t, false><<<dim3(16, 16, 1), blk, 0, stream>>>(
        bAV, bWZT, bZ, M, D, D, D, D, D, 0, 0, 0, -1, nullptr, 0);

    // ---- FFA = Z x WFFA^T ----
    gemm256d_bt<bf16_t><<<dim3(32, 8, 1), blk512, 0, stream>>>(
        bZ, bWFFAT, bFFA, D, D, D, C, 0, 0, 0, -1, nullptr, 0);

    // ---- FFB = FFA x WFFB^T, split-K=4 -> fp32 partials (plain stores) ----
    gemm256d_bt<float><<<dim3(8, 8, 4), blk512, 0, stream>>>(
        bFFA, bWFFBT, pF, 2048, C, C, D, 2048, 2048, MD, -1, nullptr, 0);

    // ---- out = sum of 4 partials ----
    reduce4_f32<<<dim3((int)(MD / 1024)), blk, 0, stream>>>(pF, out, MD);
}

// Round 4
// 602.980 us; speedup vs baseline: 1.5064x; 1.5064x over previous
//
#include <hip/hip_runtime.h>
#include <hip/hip_bf16.h>
#include <math.h>

// GPT3 block on MI355X, round 9:
//  - gemm256p_bt: faithful m201-style 8-phase schedule (hardware-verified at
//    825 cyc/phase): per phase {ds_reads -> stage 1 half -> [vmcnt gate] ->
//    barrier -> lgkmcnt(0) -> sched_barrier -> setprio(1) 16 MFMA setprio(0)
//    -> barrier}. Quadrants (0,0)(1,0)(1,1)(0,1), reads 12/8/4/8 per phase,
//    ONE af + ONE bv register set (round-8's extra sets spilled: 352MB scratch
//    writes). 4-slot half-tile ring/operand; uniform vmcnt(4) at ph4/ph8
//    (3-4 phase prefetch slack); every slot overwrite >=2 barriers after its
//    last read; tail stages clamp to the last K-tile (keeps vmcnt uniform).
//  - FFB: split-K=4 into fp32 partials + fused reduce4 (no atomics).
//  - Z-projection keeps the 128^2 m97 kernel; attention unchanged.
// ws 144 MiB: bI bWQ bWK bWV | bQ bK bVT bAV bZ bWZT | bWFFAT bWFFBT
// bFFA aliases [0,32MiB). FFB partials alias [32,96MiB) (dead by then).

typedef __bf16 bf16_t;
typedef __bf16 bf16x8 __attribute__((ext_vector_type(8)));
typedef float  f32x4  __attribute__((ext_vector_type(4)));

#define AS1 __attribute__((address_space(1)))
#define AS3 __attribute__((address_space(3)))

__device__ __forceinline__ void load16_lds(const bf16_t* g, bf16_t* l) {
    // 16B per lane, LDS dest = wave-uniform base + lane*16
    __builtin_amdgcn_global_load_lds((AS1 void*)g, (AS3 void*)l, 16, 0, 0);
}

// ---- half-tile staging (slot = 128 rows x 64 cols, 16KB) ----
// A half h = logical rows {r : (r>>6)&1 == h} (bit6 partition)
// B half h = logical rows {r : (r>>5)&1 == h} (bit5 partition)
// chunk c of phys row p holds logical chunk c ^ (p&7)  (read-side XOR swizzle)
__device__ __forceinline__ void stageA_half(const bf16_t* __restrict__ Ab, int lda,
                                            int k0, int h, bf16_t* slot,
                                            int w, int lane)
{
    #pragma unroll
    for (int j = 0; j < 2; ++j) {
        const int prw = j * 64 + w * 8;          // wave-uniform phys row base
        const int p   = prw + (lane >> 3);
        const int lr  = (p >> 6) * 128 + h * 64 + (p & 63);
        const int lc  = (lane & 7) ^ (p & 7);
        load16_lds(Ab + (long long)lr * lda + k0 + lc * 8, slot + prw * 64);
    }
}
__device__ __forceinline__ void stageB_half(const bf16_t* __restrict__ Bb, int ldb,
                                            int k0, int h, bf16_t* slot,
                                            int w, int lane)
{
    #pragma unroll
    for (int j = 0; j < 2; ++j) {
        const int prw = j * 64 + w * 8;
        const int p   = prw + (lane >> 3);
        const int lr  = (p >> 5) * 64 + h * 32 + (p & 31);
        const int lc  = (lane & 7) ^ (p & 7);
        load16_lds(Bb + (long long)lr * ldb + k0 + lc * 8, slot + prw * 64);
    }
}

#define LOADAF(DST, SL)                                                        \
  _Pragma("unroll") for (int ks = 0; ks < 2; ++ks)                             \
  _Pragma("unroll") for (int mi = 0; mi < 4; ++mi)                             \
      DST[ks][mi] = *(const bf16x8*)&(SL)[(wm * 64 + mi * 16 + c15) * 64 +     \
                      (((ks * 4 + q4) ^ (c15 & 7)) * 8)];

#define LOADBV(DST, SL)                                                        \
  _Pragma("unroll") for (int ks = 0; ks < 2; ++ks)                             \
  _Pragma("unroll") for (int nj = 0; nj < 2; ++nj)                             \
      DST[ks][nj] = *(const bf16x8*)&(SL)[(wn * 32 + nj * 16 + c15) * 64 +     \
                      (((ks * 4 + q4) ^ (c15 & 7)) * 8)];

#define MFMA8(R0, C0)                                                          \
  _Pragma("unroll") for (int ks = 0; ks < 2; ++ks)                             \
  _Pragma("unroll") for (int mi = 0; mi < 4; ++mi)                             \
  _Pragma("unroll") for (int nj = 0; nj < 2; ++nj)                             \
      acc[(R0) + mi][(C0) + nj] = __builtin_amdgcn_mfma_f32_16x16x32_bf16(     \
          af[ks][mi], bv[ks][nj], acc[(R0) + mi][(C0) + nj], 0, 0, 0);

#define VMW(N)  asm volatile("s_waitcnt vmcnt(" #N ")" ::: "memory")
#define BAR()   __builtin_amdgcn_s_barrier()

// phase: reads -> stage -> [gate] -> barrier -> lgkm(0) -> sched_barrier ->
//        setprio(1) 16xMFMA setprio(0) -> barrier
#define PHASE8(RDS, STGS, GATE, R0, C0)                                        \
  RDS;                                                                         \
  STGS;                                                                        \
  GATE;                                                                        \
  __builtin_amdgcn_s_barrier();                                                \
  asm volatile("s_waitcnt lgkmcnt(0)" ::: "memory");                           \
  __builtin_amdgcn_sched_barrier(0);                                           \
  __builtin_amdgcn_s_setprio(1);                                               \
  MFMA8(R0, C0);                                                               \
  __builtin_amdgcn_s_setprio(0);                                               \
  __builtin_amdgcn_s_barrier();

// ---------------- 256x256 8-phase GEMM (m201 schedule) ----------------
// C = A * B^T: A [M,K] lda, B [N,K] ldb, C [M,N] ldc. 512 thr = 8 waves
// (2M x 4N), per-wave C 128x64, BK=64 in A/B halves. Requires NT even, >=4.
// Slot map: half h of K-tile u -> slot (2u+h)&3 (per operand).
// Iter i covers tiles u=2i (slots 0,1) and u+1 (slots 2,3).
// Stage schedule: ph1 A0(u+1) ph2 B1(u+1) ph3 B0(u+2) ph4 A1(u+2)
//                 ph5 A0(u+2) ph6 B1(u+2) ph7 B0(u+3) ph8 A1(u+3)
// Gates: vmcnt(4) at ph4/ph8 retire exactly the 4 halves the next 4 phases
// read (3-4 phases of slack); all slot overwrites are >=2 barriers after the
// previous contents' last ds_read (liveness proven per-phase).
template<typename TOUT>
__global__ __launch_bounds__(512, 2)
void gemm256p_bt(const bf16_t* __restrict__ A, const bf16_t* __restrict__ B,
                 TOUT* __restrict__ Cc, int Kdim,
                 int lda, int ldb, int ldc,
                 long long ab, long long bb, long long cb,
                 int ct_z, bf16_t* __restrict__ ctc, int ldct)
{
    __shared__ __attribute__((aligned(16))) bf16_t As4[4][128 * 64];
    __shared__ __attribute__((aligned(16))) bf16_t Bs4[4][128 * 64];

    const int z = blockIdx.z;
    A  += (long long)z * ab;
    B  += (long long)z * bb;
    Cc += (long long)z * cb;

    const int bm = blockIdx.y * 256;
    const int bn = blockIdx.x * 256;
    const int t = threadIdx.x, lane = t & 63, w = t >> 6;
    const int wm = w >> 2, wn = w & 3;
    const int q4 = lane >> 4, c15 = lane & 15;

    const bf16_t* Ab = A + (long long)bm * lda;
    const bf16_t* Bb = B + (long long)bn * ldb;

    f32x4  acc[8][4] = {};
    bf16x8 af[2][4];   // one A fragment set (re-read at ph4/ph8: +8 reads, -64 VGPR)
    bf16x8 bv[2][2];   // one B fragment set

    // ---- prologue, steady-state stage order:
    // B0(0) A1(0) A0(0) B1(0) B0(1) A1(1)  (12 loads)
    stageB_half(Bb, ldb, 0,  0, Bs4[0], w, lane);
    stageA_half(Ab, lda, 0,  1, As4[1], w, lane);
    stageA_half(Ab, lda, 0,  0, As4[0], w, lane);
    stageB_half(Bb, ldb, 0,  1, Bs4[1], w, lane);
    stageB_half(Bb, ldb, 64, 0, Bs4[2], w, lane);
    stageA_half(Ab, lda, 64, 1, As4[3], w, lane);
    VMW(4);            // retire B0(0) A1(0) A0(0) B1(0); leave B0(1) A1(1)
    BAR();

    const int NT = Kdim >> 6;          // even, >= 4
    const int kcap = (NT - 1) << 6;

    for (int i = 0; i < NT / 2; ++i) {
        const int u  = 2 * i;
        const int k1 = (u + 1) << 6;   // always in range (u <= NT-2)
        int k2 = (u + 2) << 6; if (k2 > kcap) k2 = kcap;   // tail clamp (junk
        int k3 = (u + 3) << 6; if (k3 > kcap) k3 = kcap;   // lands in dead slots)
        // ph1: q(0,0) = A0(u) x B0(u)
        PHASE8( LOADAF(af, As4[0]); LOADBV(bv, Bs4[0]),
                stageA_half(Ab, lda, k1, 0, As4[2], w, lane), ((void)0), 0, 0)
        // ph2: q(1,0) = A1(u) x B0(u)   [bv held]
        PHASE8( LOADAF(af, As4[1]),
                stageB_half(Bb, ldb, k1, 1, Bs4[3], w, lane), ((void)0), 4, 0)
        // ph3: q(1,1) = A1(u) x B1(u)   [af held]
        PHASE8( LOADBV(bv, Bs4[1]),
                stageB_half(Bb, ldb, k2, 0, Bs4[0], w, lane), ((void)0), 4, 2)
        // ph4: q(0,1) = A0(u) x B1(u)   [bv held, af re-read]
        PHASE8( LOADAF(af, As4[0]),
                stageA_half(Ab, lda, k2, 1, As4[1], w, lane), VMW(4), 0, 2)
        // ph5: q(0,0) = A0(u+1) x B0(u+1)
        PHASE8( LOADAF(af, As4[2]); LOADBV(bv, Bs4[2]),
                stageA_half(Ab, lda, k2, 0, As4[0], w, lane), ((void)0), 0, 0)
        // ph6: q(1,0)
        PHASE8( LOADAF(af, As4[3]),
                stageB_half(Bb, ldb, k2, 1, Bs4[1], w, lane), ((void)0), 4, 0)
        // ph7: q(1,1)
        PHASE8( LOADBV(bv, Bs4[3]),
                stageB_half(Bb, ldb, k3, 0, Bs4[2], w, lane), ((void)0), 4, 2)
        // ph8: q(0,1)
        PHASE8( LOADAF(af, As4[2]),
                stageA_half(Ab, lda, k3, 1, As4[3], w, lane), VMW(4), 0, 2)
    }
    VMW(0);   // drain tail junk stages before exit

    // ---- epilogue. C/D layout: col = lane&15, row = (lane>>4)*4 + reg ----
    const int rb = q4 * 4;
    if (z == ct_z) {
        // write C^T[n][m] as bf16; 4 consecutive m -> one 8B store
        #pragma unroll
        for (int mi = 0; mi < 8; ++mi) {
            const long long mb = bm + wm * 128 + mi * 16 + rb;
            #pragma unroll
            for (int nj = 0; nj < 4; ++nj) {
                const long long n = bn + wn * 64 + nj * 16 + c15;
                union { bf16_t b[4]; unsigned long long u; } o;
                #pragma unroll
                for (int r = 0; r < 4; ++r) o.b[r] = (bf16_t)acc[mi][nj][r];
                *(unsigned long long*)(ctc + n * ldct + mb) = o.u;
            }
        }
    } else {
        #pragma unroll
        for (int mi = 0; mi < 8; ++mi) {
            #pragma unroll
            for (int r = 0; r < 4; ++r) {
                const long long m = bm + wm * 128 + mi * 16 + rb + r;
                TOUT* crow = Cc + m * ldc + bn + wn * 64 + c15;
                #pragma unroll
                for (int nj = 0; nj < 4; ++nj)
                    crow[nj * 16] = (TOUT)acc[mi][nj][r];
            }
        }
    }
}

// ---------------- GEMM (m97 structure, kept for the 64-tile Z-proj) --------
template<typename TOUT, bool ATOMIC>
__global__ __launch_bounds__(256)
void gemm_bt(const bf16_t* __restrict__ A, const bf16_t* __restrict__ B,
             TOUT* __restrict__ Cc, int Mdim, int Ndim, int Kdim,
             int lda, int ldb, int ldc,
             long long ab, long long bb, long long cb,
             int ct_z, bf16_t* __restrict__ ctc, int ldct)
{
    __shared__ bf16_t Ash[128 * 32];
    __shared__ bf16_t Bsh[128 * 32];

    const int z = blockIdx.z;
    A  += (long long)z * ab;
    B  += (long long)z * bb;
    Cc += (long long)z * cb;

    const int bm = blockIdx.y * 128;
    const int bn = blockIdx.x * 128;
    const int t  = threadIdx.x;
    const int lane = t & 63;
    const int w    = t >> 6;

    const int wm = (w & 1) * 64;
    const int wn = (w >> 1) * 64;

    const int sub = lane >> 2;
    const int seg = lane & 3;

    const bf16_t* Ag0 = A + (long long)(bm + w * 32 + sub) * lda + seg * 8;
    const bf16_t* Ag1 = Ag0 + 16LL * lda;
    const bf16_t* Bg0 = B + (long long)(bn + w * 32 + sub) * ldb + seg * 8;
    const bf16_t* Bg1 = Bg0 + 16LL * ldb;

    bf16_t* Al0 = &Ash[(w * 2 + 0) * 512];
    bf16_t* Al1 = &Ash[(w * 2 + 1) * 512];
    bf16_t* Bl0 = &Bsh[(w * 2 + 0) * 512];
    bf16_t* Bl1 = &Bsh[(w * 2 + 1) * 512];

    const int col  = lane & 15;
    const int koff = (lane >> 4) * 8;

    f32x4 acc[4][4] = {};

    for (int k0 = 0; k0 < Kdim; k0 += 32) {
        load16_lds(Ag0 + k0, Al0);
        load16_lds(Ag1 + k0, Al1);
        load16_lds(Bg0 + k0, Bl0);
        load16_lds(Bg1 + k0, Bl1);
        __syncthreads();

        bf16x8 afr[4], bfr[4];
        #pragma unroll
        for (int mi = 0; mi < 4; ++mi)
            afr[mi] = *(const bf16x8*)&Ash[(wm + mi * 16 + col) * 32 + koff];
        #pragma unroll
        for (int nj = 0; nj < 4; ++nj)
            bfr[nj] = *(const bf16x8*)&Bsh[(wn + nj * 16 + col) * 32 + koff];
        #pragma unroll
        for (int mi = 0; mi < 4; ++mi)
            #pragma unroll
            for (int nj = 0; nj < 4; ++nj)
                acc[mi][nj] = __builtin_amdgcn_mfma_f32_16x16x32_bf16(
                    afr[mi], bfr[nj], acc[mi][nj], 0, 0, 0);
        __syncthreads();
    }

    const int rbase = (lane >> 4) * 4;
    if (z == ct_z) {
        #pragma unroll
        for (int mi = 0; mi < 4; ++mi) {
            const long long mb = bm + wm + mi * 16 + rbase;
            #pragma unroll
            for (int nj = 0; nj < 4; ++nj) {
                const long long n = bn + wn + nj * 16 + col;
                union { bf16_t b[4]; unsigned long long u; } o;
                #pragma unroll
                for (int r = 0; r < 4; ++r) o.b[r] = (bf16_t)acc[mi][nj][r];
                *(unsigned long long*)(ctc + n * ldct + mb) = o.u;
            }
        }
    } else {
        #pragma unroll
        for (int mi = 0; mi < 4; ++mi) {
            #pragma unroll
            for (int r = 0; r < 4; ++r) {
                long long m = bm + wm + mi * 16 + rbase + r;
                TOUT* crow = Cc + m * ldc + bn + wn + col;
                #pragma unroll
                for (int nj = 0; nj < 4; ++nj) {
                    if constexpr (ATOMIC)
                        atomicAdd(&crow[nj * 16], (float)acc[mi][nj][r]);
                    else
                        crow[nj * 16] = (TOUT)acc[mi][nj][r];
                }
            }
        }
    }
}

// ---------------- flash attention ----------------
// Grid (M/64, H). Block 256 = 4 waves; wave owns 16 q-rows. KV tile = 64.
__global__ __launch_bounds__(256, 2)
void flash_attn(const bf16_t* __restrict__ Q, const bf16_t* __restrict__ K,
                const bf16_t* __restrict__ VT, bf16_t* __restrict__ O,
                int M, int D)
{
    __shared__ bf16_t Kt[64 * 128];
    __shared__ bf16_t Vt[128 * 64];
    __shared__ bf16_t Pl[4 * 16 * 88];

    const int t = threadIdx.x, lane = t & 63, w = t >> 6;
    const int q4 = lane >> 4;
    const int c  = lane & 15;
    const int bm = blockIdx.x * 64;
    const int hE = blockIdx.y * 128;

    bf16x8 af_q[4];
    {
        const bf16_t* qrow = Q + (long long)(bm + w * 16 + c) * D + hE + q4 * 8;
        #pragma unroll
        for (int ks = 0; ks < 4; ++ks)
            af_q[ks] = *(const bf16x8*)(qrow + ks * 32);
    }

    f32x4 acc_o[8] = {};
    float m_i[4] = {-INFINITY, -INFINITY, -INFINITY, -INFINITY};
    float l_i[4] = {0.f, 0.f, 0.f, 0.f};

    bf16_t* Pw = &Pl[w * 16 * 88];

    for (int p0 = 0; p0 < M; p0 += 64) {
        #pragma unroll
        for (int j = 0; j < 4; ++j) {
            int krow = w * 16 + j * 4;
            load16_lds(K + (long long)(p0 + krow + q4) * D + hE + ((c ^ (j * 4 + q4)) * 8),
                       &Kt[krow * 128]);
            int vrow = w * 32 + j * 8;
            load16_lds(VT + (long long)(hE + vrow + (lane >> 3)) * M + p0
                          + (((lane & 7) ^ (lane >> 3)) * 8),
                       &Vt[vrow * 64]);
        }
        __syncthreads();

        f32x4 acc_s[4] = {};
        #pragma unroll
        for (int ks = 0; ks < 4; ++ks) {
            #pragma unroll
            for (int nj = 0; nj < 4; ++nj) {
                int row = nj * 16 + c;
                bf16x8 bk = *(const bf16x8*)&Kt[row * 128 + (((ks * 4 + q4) ^ c) * 8)];
                acc_s[nj] = __builtin_amdgcn_mfma_f32_16x16x32_bf16(
                    af_q[ks], bk, acc_s[nj], 0, 0, 0);
            }
        }

        float mt[4], alpha[4], rs[4];
        #pragma unroll
        for (int r = 0; r < 4; ++r) {
            float v = fmaxf(fmaxf(acc_s[0][r], acc_s[1][r]),
                            fmaxf(acc_s[2][r], acc_s[3][r]));
            #pragma unroll
            for (int off = 1; off < 16; off <<= 1)
                v = fmaxf(v, __shfl_xor(v, off));
            mt[r] = v;
        }
        #pragma unroll
        for (int r = 0; r < 4; ++r) {
            float mn = fmaxf(m_i[r], mt[r]);
            alpha[r] = __expf(m_i[r] - mn);
            m_i[r] = mn;
            rs[r] = 0.f;
        }
        #pragma unroll
        for (int nj = 0; nj < 4; ++nj)
            #pragma unroll
            for (int r = 0; r < 4; ++r) {
                float p = __expf(acc_s[nj][r] - m_i[r]);
                rs[r] += p;
                Pw[(q4 * 4 + r) * 88 + nj * 16 + c] = (bf16_t)p;
            }
        #pragma unroll
        for (int r = 0; r < 4; ++r) {
            float v = rs[r];
            #pragma unroll
            for (int off = 1; off < 16; off <<= 1)
                v += __shfl_xor(v, off);
            l_i[r] = alpha[r] * l_i[r] + v;
        }
        #pragma unroll
        for (int nj = 0; nj < 8; ++nj)
            #pragma unroll
            for (int r = 0; r < 4; ++r)
                acc_o[nj][r] *= alpha[r];
        __syncthreads();

        #pragma unroll
        for (int ks = 0; ks < 2; ++ks) {
            bf16x8 ap = *(const bf16x8*)&Pw[c * 88 + ks * 32 + q4 * 8];
            #pragma unroll
            for (int nj = 0; nj < 8; ++nj) {
                int row = nj * 16 + c;
                bf16x8 bvv = *(const bf16x8*)&Vt[row * 64 + (((ks * 4 + q4) ^ (c & 7)) * 8)];
                acc_o[nj] = __builtin_amdgcn_mfma_f32_16x16x32_bf16(
                    ap, bvv, acc_o[nj], 0, 0, 0);
            }
        }
        __syncthreads();
    }

    float inv[4];
    #pragma unroll
    for (int r = 0; r < 4; ++r) inv[r] = 1.0f / l_i[r];
    #pragma unroll
    for (int nj = 0; nj < 8; ++nj)
        #pragma unroll
        for (int r = 0; r < 4; ++r)
            O[(long long)(bm + w * 16 + q4 * 4 + r) * D + hE + nj * 16 + c] =
                (bf16_t)(acc_o[nj][r] * inv[r]);
}

// ---------------- small utility kernels ----------------
__global__ __launch_bounds__(256)
void cast4_bf16(const float* __restrict__ s0, const float* __restrict__ s1,
                const float* __restrict__ s2, const float* __restrict__ s3,
                bf16_t* __restrict__ d0, long long seg, long long n)
{
    const float* src = (blockIdx.y == 0) ? s0 : (blockIdx.y == 1) ? s1
                     : (blockIdx.y == 2) ? s2 : s3;
    bf16_t* dst = d0 + (long long)blockIdx.y * seg;
    long long i = ((long long)blockIdx.x * 256 + threadIdx.x) * 4;
    if (i >= n) return;
    float4 v = *(const float4*)(src + i);
    union { bf16_t b[4]; unsigned long long u; } o;
    o.b[0] = (bf16_t)v.x; o.b[1] = (bf16_t)v.y;
    o.b[2] = (bf16_t)v.z; o.b[3] = (bf16_t)v.w;
    *(unsigned long long*)(dst + i) = o.u;
}

__global__ __launch_bounds__(256)
void transpose_to_bf16(const float* __restrict__ in, bf16_t* __restrict__ out,
                       int rows, int cols)
{
    __shared__ bf16_t tile[32][33];
    const int r0 = blockIdx.y * 32, c0 = blockIdx.x * 32;
    const int tx = threadIdx.x & 31, ty = threadIdx.x >> 5;
    #pragma unroll
    for (int i = 0; i < 4; ++i) {
        int r = ty + i * 8;
        tile[r][tx] = (bf16_t)in[(long long)(r0 + r) * cols + c0 + tx];
    }
    __syncthreads();
    #pragma unroll
    for (int i = 0; i < 4; ++i) {
        int r = ty + i * 8;
        out[(long long)(c0 + r) * rows + r0 + tx] = tile[tx][r];
    }
}

__global__ __launch_bounds__(256)
void reduce4_f32(const float* __restrict__ p, float* __restrict__ out,
                 long long n)
{
    long long i = ((long long)blockIdx.x * 256 + threadIdx.x) * 4;
    if (i >= n) return;
    float4 a = *(const float4*)(p + i);
    float4 b = *(const float4*)(p + n + i);
    float4 c = *(const float4*)(p + 2 * n + i);
    float4 d = *(const float4*)(p + 3 * n + i);
    float4 o;
    o.x = a.x + b.x + c.x + d.x;
    o.y = a.y + b.y + c.y + d.y;
    o.z = a.z + b.z + c.z + d.z;
    o.w = a.w + b.w + c.w + d.w;
    *(float4*)(out + i) = o;
}

extern "C" void kernel_launch(void* const* d_in, const int* in_sizes, int n_in,
                              void* d_out, int out_size, void* d_ws, size_t ws_size,
                              hipStream_t stream)
{
    const float* I    = (const float*)d_in[0];
    const float* WV   = (const float*)d_in[1];
    const float* WK   = (const float*)d_in[2];
    const float* WQ   = (const float*)d_in[3];
    const float* WZ   = (const float*)d_in[4];
    const float* WFFA = (const float*)d_in[5];
    const float* WFFB = (const float*)d_in[6];
    float* out = (float*)d_out;                  // [M, D] fp32

    const int M = 2048, D = 2048, C = 8192;
    const long long MD = (long long)M * D;
    const size_t MiB = 1024 * 1024;

    char* base = (char*)d_ws;
    bf16_t* bI     = (bf16_t*)(base + 0 * MiB);
    bf16_t* bWQ    = (bf16_t*)(base + 8 * MiB);    // contiguous WQ,WK,WV (z-batch)
    bf16_t* bWK    = (bf16_t*)(base + 16 * MiB);
    bf16_t* bWV    = (bf16_t*)(base + 24 * MiB);
    bf16_t* bQ     = (bf16_t*)(base + 32 * MiB);   // contiguous Q,K (z-batch out)
    bf16_t* bK     = (bf16_t*)(base + 40 * MiB);
    bf16_t* bVT    = (bf16_t*)(base + 48 * MiB);   // [D, M] via ct_z epilogue
    bf16_t* bAV    = (bf16_t*)(base + 56 * MiB);
    bf16_t* bZ     = (bf16_t*)(base + 64 * MiB);
    bf16_t* bWZT   = (bf16_t*)(base + 72 * MiB);
    bf16_t* bWFFAT = (bf16_t*)(base + 80 * MiB);   // [C, D]
    bf16_t* bWFFBT = (bf16_t*)(base + 112 * MiB);  // [D, C]
    bf16_t* bFFA   = (bf16_t*)(base + 0 * MiB);    // [M, C] bf16 (bI..bWV dead)
    float*  pF     = (float*)(base + 32 * MiB);    // 4x [M,D] fp32 FFB partials

    const dim3 blk(256);
    const dim3 blk512(512);

    // ---- prep: casts + weight transposes ----
    cast4_bf16<<<dim3(MD / 1024, 4), blk, 0, stream>>>(I, WQ, WK, WV, bI, MD, MD);
    transpose_to_bf16<<<dim3(D / 32, D / 32), blk, 0, stream>>>(WZ,   bWZT,   D, D);
    transpose_to_bf16<<<dim3(C / 32, D / 32), blk, 0, stream>>>(WFFA, bWFFAT, D, C);
    transpose_to_bf16<<<dim3(D / 32, C / 32), blk, 0, stream>>>(WFFB, bWFFBT, C, D);

    // ---- QKV in one z=3 dispatch; V -> bVT transposed ----
    gemm256p_bt<bf16_t><<<dim3(8, 8, 3), blk512, 0, stream>>>(
        bI, bWQ, bQ, D, D, D, D, 0, MD, MD, /*ct_z=*/2, bVT, M);

    // ---- flash attention: Q,K,VT -> AV ----
    flash_attn<<<dim3(M / 64, 16), blk, 0, stream>>>(bQ, bK, bVT, bAV, M, D);

    // ---- Z = AV x WZ^T (64 tiles at 256^2 -> keep 128^2 kernel) ----
    gemm_bt<bf16_t, false><<<dim3(16, 16, 1), blk, 0, stream>>>(
        bAV, bWZT, bZ, M, D, D, D, D, D, 0, 0, 0, -1, nullptr, 0);

    // ---- FFA = Z x WFFA^T ----
    gemm256p_bt<bf16_t><<<dim3(32, 8, 1), blk512, 0, stream>>>(
        bZ, bWFFAT, bFFA, D, D, D, C, 0, 0, 0, -1, nullptr, 0);

    // ---- FFB = FFA x WFFB^T, split-K=4 -> fp32 partials (plain stores) ----
    gemm256p_bt<float><<<dim3(8, 8, 4), blk512, 0, stream>>>(
        bFFA, bWFFBT, pF, 2048, C, C, D, 2048, 2048, MD, -1, nullptr, 0);

    // ---- out = sum of 4 partials ----
    reduce4_f32<<<dim3((int)(MD / 1024)), blk, 0, stream>>>(pF, out, MD);
}

// Round 5
// 599.355 us; speedup vs baseline: 1.5156x; 1.0060x over previous
//
#include <hip/hip_runtime.h>
#include <hip/hip_bf16.h>
#include <math.h>

// GPT3 block on MI355X, round 10:
//  - flash_attn v2: double-buffered K/V tiles + counted vmcnt(8) (stage for
//    tile t+1 issued at top of iter t -> a full iteration of latency cover),
//    P-visibility barrier replaced by lgkmcnt(0) (P is same-wave only),
//    2 barriers/iter (was 3 + vmcnt(0) drain every iter), setprio around both
//    MFMA clusters. Round-9 counters: 96us, MfmaUtil 14%, ~7200cyc/iter vs
//    ~1500 busy -> stall-dominated, same disease the GEMMs had.
//  - gemm256p_bt (8-phase m201 schedule) for QKV/FFA/FFB unchanged.
//  - FFB: split-K=4 into fp32 partials + fused reduce4 (no atomics).
//  - Z-projection keeps the 128^2 m97 kernel.
// ws 144 MiB: bI bWQ bWK bWV | bQ bK bVT bAV bZ bWZT | bWFFAT bWFFBT
// bFFA aliases [0,32MiB). FFB partials alias [32,96MiB) (dead by then).

typedef __bf16 bf16_t;
typedef __bf16 bf16x8 __attribute__((ext_vector_type(8)));
typedef float  f32x4  __attribute__((ext_vector_type(4)));

#define AS1 __attribute__((address_space(1)))
#define AS3 __attribute__((address_space(3)))

__device__ __forceinline__ void load16_lds(const bf16_t* g, bf16_t* l) {
    // 16B per lane, LDS dest = wave-uniform base + lane*16
    __builtin_amdgcn_global_load_lds((AS1 void*)g, (AS3 void*)l, 16, 0, 0);
}

// ---- half-tile staging (slot = 128 rows x 64 cols, 16KB) ----
// A half h = logical rows {r : (r>>6)&1 == h} (bit6 partition)
// B half h = logical rows {r : (r>>5)&1 == h} (bit5 partition)
// chunk c of phys row p holds logical chunk c ^ (p&7)  (read-side XOR swizzle)
__device__ __forceinline__ void stageA_half(const bf16_t* __restrict__ Ab, int lda,
                                            int k0, int h, bf16_t* slot,
                                            int w, int lane)
{
    #pragma unroll
    for (int j = 0; j < 2; ++j) {
        const int prw = j * 64 + w * 8;          // wave-uniform phys row base
        const int p   = prw + (lane >> 3);
        const int lr  = (p >> 6) * 128 + h * 64 + (p & 63);
        const int lc  = (lane & 7) ^ (p & 7);
        load16_lds(Ab + (long long)lr * lda + k0 + lc * 8, slot + prw * 64);
    }
}
__device__ __forceinline__ void stageB_half(const bf16_t* __restrict__ Bb, int ldb,
                                            int k0, int h, bf16_t* slot,
                                            int w, int lane)
{
    #pragma unroll
    for (int j = 0; j < 2; ++j) {
        const int prw = j * 64 + w * 8;
        const int p   = prw + (lane >> 3);
        const int lr  = (p >> 5) * 64 + h * 32 + (p & 31);
        const int lc  = (lane & 7) ^ (p & 7);
        load16_lds(Bb + (long long)lr * ldb + k0 + lc * 8, slot + prw * 64);
    }
}

#define LOADAF(DST, SL)                                                        \
  _Pragma("unroll") for (int ks = 0; ks < 2; ++ks)                             \
  _Pragma("unroll") for (int mi = 0; mi < 4; ++mi)                             \
      DST[ks][mi] = *(const bf16x8*)&(SL)[(wm * 64 + mi * 16 + c15) * 64 +     \
                      (((ks * 4 + q4) ^ (c15 & 7)) * 8)];

#define LOADBV(DST, SL)                                                        \
  _Pragma("unroll") for (int ks = 0; ks < 2; ++ks)                             \
  _Pragma("unroll") for (int nj = 0; nj < 2; ++nj)                             \
      DST[ks][nj] = *(const bf16x8*)&(SL)[(wn * 32 + nj * 16 + c15) * 64 +     \
                      (((ks * 4 + q4) ^ (c15 & 7)) * 8)];

#define MFMA8(R0, C0)                                                          \
  _Pragma("unroll") for (int ks = 0; ks < 2; ++ks)                             \
  _Pragma("unroll") for (int mi = 0; mi < 4; ++mi)                             \
  _Pragma("unroll") for (int nj = 0; nj < 2; ++nj)                             \
      acc[(R0) + mi][(C0) + nj] = __builtin_amdgcn_mfma_f32_16x16x32_bf16(     \
          af[ks][mi], bv[ks][nj], acc[(R0) + mi][(C0) + nj], 0, 0, 0);

#define VMW(N)  asm volatile("s_waitcnt vmcnt(" #N ")" ::: "memory")
#define LGKM0() asm volatile("s_waitcnt lgkmcnt(0)" ::: "memory")
#define BAR()   __builtin_amdgcn_s_barrier()

// phase: reads -> stage -> [gate] -> barrier -> lgkm(0) -> sched_barrier ->
//        setprio(1) 16xMFMA setprio(0) -> barrier
#define PHASE8(RDS, STGS, GATE, R0, C0)                                        \
  RDS;                                                                         \
  STGS;                                                                        \
  GATE;                                                                        \
  __builtin_amdgcn_s_barrier();                                                \
  asm volatile("s_waitcnt lgkmcnt(0)" ::: "memory");                           \
  __builtin_amdgcn_sched_barrier(0);                                           \
  __builtin_amdgcn_s_setprio(1);                                               \
  MFMA8(R0, C0);                                                               \
  __builtin_amdgcn_s_setprio(0);                                               \
  __builtin_amdgcn_s_barrier();

// ---------------- 256x256 8-phase GEMM (m201 schedule) ----------------
// C = A * B^T: A [M,K] lda, B [N,K] ldb, C [M,N] ldc. 512 thr = 8 waves
// (2M x 4N), per-wave C 128x64, BK=64 in A/B halves. Requires NT even, >=4.
template<typename TOUT>
__global__ __launch_bounds__(512, 2)
void gemm256p_bt(const bf16_t* __restrict__ A, const bf16_t* __restrict__ B,
                 TOUT* __restrict__ Cc, int Kdim,
                 int lda, int ldb, int ldc,
                 long long ab, long long bb, long long cb,
                 int ct_z, bf16_t* __restrict__ ctc, int ldct)
{
    __shared__ __attribute__((aligned(16))) bf16_t As4[4][128 * 64];
    __shared__ __attribute__((aligned(16))) bf16_t Bs4[4][128 * 64];

    const int z = blockIdx.z;
    A  += (long long)z * ab;
    B  += (long long)z * bb;
    Cc += (long long)z * cb;

    const int bm = blockIdx.y * 256;
    const int bn = blockIdx.x * 256;
    const int t = threadIdx.x, lane = t & 63, w = t >> 6;
    const int wm = w >> 2, wn = w & 3;
    const int q4 = lane >> 4, c15 = lane & 15;

    const bf16_t* Ab = A + (long long)bm * lda;
    const bf16_t* Bb = B + (long long)bn * ldb;

    f32x4  acc[8][4] = {};
    bf16x8 af[2][4];   // one A fragment set
    bf16x8 bv[2][2];   // one B fragment set

    // prologue: B0(0) A1(0) A0(0) B1(0) B0(1) A1(1)  (12 loads)
    stageB_half(Bb, ldb, 0,  0, Bs4[0], w, lane);
    stageA_half(Ab, lda, 0,  1, As4[1], w, lane);
    stageA_half(Ab, lda, 0,  0, As4[0], w, lane);
    stageB_half(Bb, ldb, 0,  1, Bs4[1], w, lane);
    stageB_half(Bb, ldb, 64, 0, Bs4[2], w, lane);
    stageA_half(Ab, lda, 64, 1, As4[3], w, lane);
    VMW(4);
    BAR();

    const int NT = Kdim >> 6;          // even, >= 4
    const int kcap = (NT - 1) << 6;

    for (int i = 0; i < NT / 2; ++i) {
        const int u  = 2 * i;
        const int k1 = (u + 1) << 6;
        int k2 = (u + 2) << 6; if (k2 > kcap) k2 = kcap;
        int k3 = (u + 3) << 6; if (k3 > kcap) k3 = kcap;
        PHASE8( LOADAF(af, As4[0]); LOADBV(bv, Bs4[0]),
                stageA_half(Ab, lda, k1, 0, As4[2], w, lane), ((void)0), 0, 0)
        PHASE8( LOADAF(af, As4[1]),
                stageB_half(Bb, ldb, k1, 1, Bs4[3], w, lane), ((void)0), 4, 0)
        PHASE8( LOADBV(bv, Bs4[1]),
                stageB_half(Bb, ldb, k2, 0, Bs4[0], w, lane), ((void)0), 4, 2)
        PHASE8( LOADAF(af, As4[0]),
                stageA_half(Ab, lda, k2, 1, As4[1], w, lane), VMW(4), 0, 2)
        PHASE8( LOADAF(af, As4[2]); LOADBV(bv, Bs4[2]),
                stageA_half(Ab, lda, k2, 0, As4[0], w, lane), ((void)0), 0, 0)
        PHASE8( LOADAF(af, As4[3]),
                stageB_half(Bb, ldb, k2, 1, Bs4[1], w, lane), ((void)0), 4, 0)
        PHASE8( LOADBV(bv, Bs4[3]),
                stageB_half(Bb, ldb, k3, 0, Bs4[2], w, lane), ((void)0), 4, 2)
        PHASE8( LOADAF(af, As4[2]),
                stageA_half(Ab, lda, k3, 1, As4[3], w, lane), VMW(4), 0, 2)
    }
    VMW(0);   // drain tail junk stages before exit

    // ---- epilogue. C/D layout: col = lane&15, row = (lane>>4)*4 + reg ----
    const int rb = q4 * 4;
    if (z == ct_z) {
        #pragma unroll
        for (int mi = 0; mi < 8; ++mi) {
            const long long mb = bm + wm * 128 + mi * 16 + rb;
            #pragma unroll
            for (int nj = 0; nj < 4; ++nj) {
                const long long n = bn + wn * 64 + nj * 16 + c15;
                union { bf16_t b[4]; unsigned long long u; } o;
                #pragma unroll
                for (int r = 0; r < 4; ++r) o.b[r] = (bf16_t)acc[mi][nj][r];
                *(unsigned long long*)(ctc + n * ldct + mb) = o.u;
            }
        }
    } else {
        #pragma unroll
        for (int mi = 0; mi < 8; ++mi) {
            #pragma unroll
            for (int r = 0; r < 4; ++r) {
                const long long m = bm + wm * 128 + mi * 16 + rb + r;
                TOUT* crow = Cc + m * ldc + bn + wn * 64 + c15;
                #pragma unroll
                for (int nj = 0; nj < 4; ++nj)
                    crow[nj * 16] = (TOUT)acc[mi][nj][r];
            }
        }
    }
}

// ---------------- GEMM (m97 structure, kept for the 64-tile Z-proj) --------
template<typename TOUT, bool ATOMIC>
__global__ __launch_bounds__(256)
void gemm_bt(const bf16_t* __restrict__ A, const bf16_t* __restrict__ B,
             TOUT* __restrict__ Cc, int Mdim, int Ndim, int Kdim,
             int lda, int ldb, int ldc,
             long long ab, long long bb, long long cb,
             int ct_z, bf16_t* __restrict__ ctc, int ldct)
{
    __shared__ bf16_t Ash[128 * 32];
    __shared__ bf16_t Bsh[128 * 32];

    const int z = blockIdx.z;
    A  += (long long)z * ab;
    B  += (long long)z * bb;
    Cc += (long long)z * cb;

    const int bm = blockIdx.y * 128;
    const int bn = blockIdx.x * 128;
    const int t  = threadIdx.x;
    const int lane = t & 63;
    const int w    = t >> 6;

    const int wm = (w & 1) * 64;
    const int wn = (w >> 1) * 64;

    const int sub = lane >> 2;
    const int seg = lane & 3;

    const bf16_t* Ag0 = A + (long long)(bm + w * 32 + sub) * lda + seg * 8;
    const bf16_t* Ag1 = Ag0 + 16LL * lda;
    const bf16_t* Bg0 = B + (long long)(bn + w * 32 + sub) * ldb + seg * 8;
    const bf16_t* Bg1 = Bg0 + 16LL * ldb;

    bf16_t* Al0 = &Ash[(w * 2 + 0) * 512];
    bf16_t* Al1 = &Ash[(w * 2 + 1) * 512];
    bf16_t* Bl0 = &Bsh[(w * 2 + 0) * 512];
    bf16_t* Bl1 = &Bsh[(w * 2 + 1) * 512];

    const int col  = lane & 15;
    const int koff = (lane >> 4) * 8;

    f32x4 acc[4][4] = {};

    for (int k0 = 0; k0 < Kdim; k0 += 32) {
        load16_lds(Ag0 + k0, Al0);
        load16_lds(Ag1 + k0, Al1);
        load16_lds(Bg0 + k0, Bl0);
        load16_lds(Bg1 + k0, Bl1);
        __syncthreads();

        bf16x8 afr[4], bfr[4];
        #pragma unroll
        for (int mi = 0; mi < 4; ++mi)
            afr[mi] = *(const bf16x8*)&Ash[(wm + mi * 16 + col) * 32 + koff];
        #pragma unroll
        for (int nj = 0; nj < 4; ++nj)
            bfr[nj] = *(const bf16x8*)&Bsh[(wn + nj * 16 + col) * 32 + koff];
        #pragma unroll
        for (int mi = 0; mi < 4; ++mi)
            #pragma unroll
            for (int nj = 0; nj < 4; ++nj)
                acc[mi][nj] = __builtin_amdgcn_mfma_f32_16x16x32_bf16(
                    afr[mi], bfr[nj], acc[mi][nj], 0, 0, 0);
        __syncthreads();
    }

    const int rbase = (lane >> 4) * 4;
    if (z == ct_z) {
        #pragma unroll
        for (int mi = 0; mi < 4; ++mi) {
            const long long mb = bm + wm + mi * 16 + rbase;
            #pragma unroll
            for (int nj = 0; nj < 4; ++nj) {
                const long long n = bn + wn + nj * 16 + col;
                union { bf16_t b[4]; unsigned long long u; } o;
                #pragma unroll
                for (int r = 0; r < 4; ++r) o.b[r] = (bf16_t)acc[mi][nj][r];
                *(unsigned long long*)(ctc + n * ldct + mb) = o.u;
            }
        }
    } else {
        #pragma unroll
        for (int mi = 0; mi < 4; ++mi) {
            #pragma unroll
            for (int r = 0; r < 4; ++r) {
                long long m = bm + wm + mi * 16 + rbase + r;
                TOUT* crow = Cc + m * ldc + bn + wn + col;
                #pragma unroll
                for (int nj = 0; nj < 4; ++nj) {
                    if constexpr (ATOMIC)
                        atomicAdd(&crow[nj * 16], (float)acc[mi][nj][r]);
                    else
                        crow[nj * 16] = (TOUT)acc[mi][nj][r];
                }
            }
        }
    }
}

// ---------------- flash attention v2 (double-buffered, counted vmcnt) ------
// Grid (M/64, H). Block 256 = 4 waves; wave owns 16 q-rows. KV tile = 64.
// Per iter: issue stage(t+1) -> VMW(8) BAR -> QK^T -> softmax (P same-wave,
// lgkm only) -> PV -> BAR. LDS 75.25 KiB -> 2 blocks/CU.
__global__ __launch_bounds__(256, 2)
void flash_attn(const bf16_t* __restrict__ Q, const bf16_t* __restrict__ K,
                const bf16_t* __restrict__ VT, bf16_t* __restrict__ O,
                int M, int D)
{
    __shared__ bf16_t Kt[2][64 * 128];
    __shared__ bf16_t Vt[2][128 * 64];
    __shared__ bf16_t Pl[4 * 16 * 88];

    const int t = threadIdx.x, lane = t & 63, w = t >> 6;
    const int q4 = lane >> 4;
    const int c  = lane & 15;
    const int bm = blockIdx.x * 64;
    const int hE = blockIdx.y * 128;

    bf16x8 af_q[4];
    {
        const bf16_t* qrow = Q + (long long)(bm + w * 16 + c) * D + hE + q4 * 8;
        #pragma unroll
        for (int ks = 0; ks < 4; ++ks)
            af_q[ks] = *(const bf16x8*)(qrow + ks * 32);
    }

    f32x4 acc_o[8] = {};
    float m_i[4] = {-INFINITY, -INFINITY, -INFINITY, -INFINITY};
    float l_i[4] = {0.f, 0.f, 0.f, 0.f};

    bf16_t* Pw = &Pl[w * 16 * 88];

    const int NT = M >> 6;     // 32

    // stage K/V tile at row-offset p0 into buffer b (8 loads/wave)
    #define FA_STAGE(P0, B)                                                    \
      _Pragma("unroll")                                                        \
      for (int j = 0; j < 4; ++j) {                                            \
          int krow = w * 16 + j * 4;                                           \
          load16_lds(K + (long long)((P0) + krow + q4) * D + hE +              \
                         ((c ^ (j * 4 + q4)) * 8),                             \
                     &Kt[B][krow * 128]);                                      \
          int vrow = w * 32 + j * 8;                                           \
          load16_lds(VT + (long long)(hE + vrow + (lane >> 3)) * M + (P0) +    \
                         (((lane & 7) ^ (lane >> 3)) * 8),                     \
                     &Vt[B][vrow * 64]);                                       \
      }

    FA_STAGE(0, 0)

    for (int ti = 0; ti < NT; ++ti) {
        const int cur = ti & 1;
        // issue next tile's loads (tail: restage current tile into dead buf)
        const int pn = (ti + 1 < NT) ? (ti + 1) * 64 : ti * 64;
        FA_STAGE(pn, cur ^ 1)
        VMW(8);            // retire tile ti's 8 loads (issued one iter ago)
        BAR();             // all waves' contributions to Kt/Vt[cur] visible

        // ---- S = Q K^T : wave computes [16, 64] ----
        f32x4 acc_s[4] = {};
        __builtin_amdgcn_s_setprio(1);
        #pragma unroll
        for (int ks = 0; ks < 4; ++ks) {
            #pragma unroll
            for (int nj = 0; nj < 4; ++nj) {
                int row = nj * 16 + c;
                bf16x8 bk = *(const bf16x8*)&Kt[cur][row * 128 + (((ks * 4 + q4) ^ c) * 8)];
                acc_s[nj] = __builtin_amdgcn_mfma_f32_16x16x32_bf16(
                    af_q[ks], bk, acc_s[nj], 0, 0, 0);
            }
        }
        __builtin_amdgcn_s_setprio(0);

        // ---- online softmax (rows = q4*4 + r, cols across lane&15 and nj) ----
        float mt[4], alpha[4], rs[4];
        #pragma unroll
        for (int r = 0; r < 4; ++r) {
            float v = fmaxf(fmaxf(acc_s[0][r], acc_s[1][r]),
                            fmaxf(acc_s[2][r], acc_s[3][r]));
            #pragma unroll
            for (int off = 1; off < 16; off <<= 1)
                v = fmaxf(v, __shfl_xor(v, off));
            mt[r] = v;
        }
        #pragma unroll
        for (int r = 0; r < 4; ++r) {
            float mn = fmaxf(m_i[r], mt[r]);
            alpha[r] = __expf(m_i[r] - mn);
            m_i[r] = mn;
            rs[r] = 0.f;
        }
        #pragma unroll
        for (int nj = 0; nj < 4; ++nj)
            #pragma unroll
            for (int r = 0; r < 4; ++r) {
                float p = __expf(acc_s[nj][r] - m_i[r]);
                rs[r] += p;
                Pw[(q4 * 4 + r) * 88 + nj * 16 + c] = (bf16_t)p;
            }
        #pragma unroll
        for (int r = 0; r < 4; ++r) {
            float v = rs[r];
            #pragma unroll
            for (int off = 1; off < 16; off <<= 1)
                v += __shfl_xor(v, off);
            l_i[r] = alpha[r] * l_i[r] + v;
        }
        #pragma unroll
        for (int nj = 0; nj < 8; ++nj)
            #pragma unroll
            for (int r = 0; r < 4; ++r)
                acc_o[nj][r] *= alpha[r];

        // P store -> read is same-wave: lgkm wait only, no barrier
        LGKM0();
        __builtin_amdgcn_sched_barrier(0);

        // ---- O += P V : A = P [m][p], B = Vt [e][p] ----
        __builtin_amdgcn_s_setprio(1);
        #pragma unroll
        for (int ks = 0; ks < 2; ++ks) {
            bf16x8 ap = *(const bf16x8*)&Pw[c * 88 + ks * 32 + q4 * 8];
            #pragma unroll
            for (int nj = 0; nj < 8; ++nj) {
                int row = nj * 16 + c;
                bf16x8 bvv = *(const bf16x8*)&Vt[cur][row * 64 + (((ks * 4 + q4) ^ (c & 7)) * 8)];
                acc_o[nj] = __builtin_amdgcn_mfma_f32_16x16x32_bf16(
                    ap, bvv, acc_o[nj], 0, 0, 0);
            }
        }
        __builtin_amdgcn_s_setprio(0);
        BAR();             // all reads of buf[cur] done before next overwrite
    }
    VMW(0);                // drain tail junk stages before LDS goes away

    float inv[4];
    #pragma unroll
    for (int r = 0; r < 4; ++r) inv[r] = 1.0f / l_i[r];
    #pragma unroll
    for (int nj = 0; nj < 8; ++nj)
        #pragma unroll
        for (int r = 0; r < 4; ++r)
            O[(long long)(bm + w * 16 + q4 * 4 + r) * D + hE + nj * 16 + c] =
                (bf16_t)(acc_o[nj][r] * inv[r]);
    #undef FA_STAGE
}

// ---------------- small utility kernels ----------------
__global__ __launch_bounds__(256)
void cast4_bf16(const float* __restrict__ s0, const float* __restrict__ s1,
                const float* __restrict__ s2, const float* __restrict__ s3,
                bf16_t* __restrict__ d0, long long seg, long long n)
{
    const float* src = (blockIdx.y == 0) ? s0 : (blockIdx.y == 1) ? s1
                     : (blockIdx.y == 2) ? s2 : s3;
    bf16_t* dst = d0 + (long long)blockIdx.y * seg;
    long long i = ((long long)blockIdx.x * 256 + threadIdx.x) * 4;
    if (i >= n) return;
    float4 v = *(const float4*)(src + i);
    union { bf16_t b[4]; unsigned long long u; } o;
    o.b[0] = (bf16_t)v.x; o.b[1] = (bf16_t)v.y;
    o.b[2] = (bf16_t)v.z; o.b[3] = (bf16_t)v.w;
    *(unsigned long long*)(dst + i) = o.u;
}

__global__ __launch_bounds__(256)
void transpose_to_bf16(const float* __restrict__ in, bf16_t* __restrict__ out,
                       int rows, int cols)
{
    __shared__ bf16_t tile[32][33];
    const int r0 = blockIdx.y * 32, c0 = blockIdx.x * 32;
    const int tx = threadIdx.x & 31, ty = threadIdx.x >> 5;
    #pragma unroll
    for (int i = 0; i < 4; ++i) {
        int r = ty + i * 8;
        tile[r][tx] = (bf16_t)in[(long long)(r0 + r) * cols + c0 + tx];
    }
    __syncthreads();
    #pragma unroll
    for (int i = 0; i < 4; ++i) {
        int r = ty + i * 8;
        out[(long long)(c0 + r) * rows + r0 + tx] = tile[tx][r];
    }
}

__global__ __launch_bounds__(256)
void reduce4_f32(const float* __restrict__ p, float* __restrict__ out,
                 long long n)
{
    long long i = ((long long)blockIdx.x * 256 + threadIdx.x) * 4;
    if (i >= n) return;
    float4 a = *(const float4*)(p + i);
    float4 b = *(const float4*)(p + n + i);
    float4 c = *(const float4*)(p + 2 * n + i);
    float4 d = *(const float4*)(p + 3 * n + i);
    float4 o;
    o.x = a.x + b.x + c.x + d.x;
    o.y = a.y + b.y + c.y + d.y;
    o.z = a.z + b.z + c.z + d.z;
    o.w = a.w + b.w + c.w + d.w;
    *(float4*)(out + i) = o;
}

extern "C" void kernel_launch(void* const* d_in, const int* in_sizes, int n_in,
                              void* d_out, int out_size, void* d_ws, size_t ws_size,
                              hipStream_t stream)
{
    const float* I    = (const float*)d_in[0];
    const float* WV   = (const float*)d_in[1];
    const float* WK   = (const float*)d_in[2];
    const float* WQ   = (const float*)d_in[3];
    const float* WZ   = (const float*)d_in[4];
    const float* WFFA = (const float*)d_in[5];
    const float* WFFB = (const float*)d_in[6];
    float* out = (float*)d_out;                  // [M, D] fp32

    const int M = 2048, D = 2048, C = 8192;
    const long long MD = (long long)M * D;
    const size_t MiB = 1024 * 1024;

    char* base = (char*)d_ws;
    bf16_t* bI     = (bf16_t*)(base + 0 * MiB);
    bf16_t* bWQ    = (bf16_t*)(base + 8 * MiB);    // contiguous WQ,WK,WV (z-batch)
    bf16_t* bWK    = (bf16_t*)(base + 16 * MiB);
    bf16_t* bWV    = (bf16_t*)(base + 24 * MiB);
    bf16_t* bQ     = (bf16_t*)(base + 32 * MiB);   // contiguous Q,K (z-batch out)
    bf16_t* bK     = (bf16_t*)(base + 40 * MiB);
    bf16_t* bVT    = (bf16_t*)(base + 48 * MiB);   // [D, M] via ct_z epilogue
    bf16_t* bAV    = (bf16_t*)(base + 56 * MiB);
    bf16_t* bZ     = (bf16_t*)(base + 64 * MiB);
    bf16_t* bWZT   = (bf16_t*)(base + 72 * MiB);
    bf16_t* bWFFAT = (bf16_t*)(base + 80 * MiB);   // [C, D]
    bf16_t* bWFFBT = (bf16_t*)(base + 112 * MiB);  // [D, C]
    bf16_t* bFFA   = (bf16_t*)(base + 0 * MiB);    // [M, C] bf16 (bI..bWV dead)
    float*  pF     = (float*)(base + 32 * MiB);    // 4x [M,D] fp32 FFB partials

    const dim3 blk(256);
    const dim3 blk512(512);

    // ---- prep: casts + weight transposes ----
    cast4_bf16<<<dim3(MD / 1024, 4), blk, 0, stream>>>(I, WQ, WK, WV, bI, MD, MD);
    transpose_to_bf16<<<dim3(D / 32, D / 32), blk, 0, stream>>>(WZ,   bWZT,   D, D);
    transpose_to_bf16<<<dim3(C / 32, D / 32), blk, 0, stream>>>(WFFA, bWFFAT, D, C);
    transpose_to_bf16<<<dim3(D / 32, C / 32), blk, 0, stream>>>(WFFB, bWFFBT, C, D);

    // ---- QKV in one z=3 dispatch; V -> bVT transposed ----
    gemm256p_bt<bf16_t><<<dim3(8, 8, 3), blk512, 0, stream>>>(
        bI, bWQ, bQ, D, D, D, D, 0, MD, MD, /*ct_z=*/2, bVT, M);

    // ---- flash attention: Q,K,VT -> AV ----
    flash_attn<<<dim3(M / 64, 16), blk, 0, stream>>>(bQ, bK, bVT, bAV, M, D);

    // ---- Z = AV x WZ^T (64 tiles at 256^2 -> keep 128^2 kernel) ----
    gemm_bt<bf16_t, false><<<dim3(16, 16, 1), blk, 0, stream>>>(
        bAV, bWZT, bZ, M, D, D, D, D, D, 0, 0, 0, -1, nullptr, 0);

    // ---- FFA = Z x WFFA^T ----
    gemm256p_bt<bf16_t><<<dim3(32, 8, 1), blk512, 0, stream>>>(
        bZ, bWFFAT, bFFA, D, D, D, C, 0, 0, 0, -1, nullptr, 0);

    // ---- FFB = FFA x WFFB^T, split-K=4 -> fp32 partials (plain stores) ----
    gemm256p_bt<float><<<dim3(8, 8, 4), blk512, 0, stream>>>(
        bFFA, bWFFBT, pF, 2048, C, C, D, 2048, 2048, MD, -1, nullptr, 0);

    // ---- out = sum of 4 partials ----
    reduce4_f32<<<dim3((int)(MD / 1024)), blk, 0, stream>>>(pF, out, MD);
}

// Round 6
// 579.190 us; speedup vs baseline: 1.5683x; 1.0348x over previous
//
#include <hip/hip_runtime.h>
#include <hip/hip_bf16.h>
#include <math.h>

// GPT3 block on MI355X, round 11:
//  - flash_attn v3: DPP row_ror butterflies replace __shfl_xor reduces
//    (VALU full-rate, ~4cyc dep latency vs ds_bpermute ~60cyc, off the LDS
//    pipe) + defer-max (T13, THR=8): skip O-rescale & m-update when tile max
//    doesn't grow past m+8 (almost always after tile 0 on this data).
//  - Z-projection: moved off the 128^2 m97 kernel (49us, 320TF at K=2048)
//    to gemm256p split-K=2 (8x8x2 grid) + reduce2->bf16. Partials in
//    [0,32)MiB (dead between QKV and FFA).
//  - gemm256p_bt (8-phase m201 schedule) for QKV/FFA/FFB unchanged.
//  - FFB: split-K=4 into fp32 partials + fused reduce4 (no atomics).
// ws 144 MiB: bI bWQ bWK bWV | bQ bK bVT bAV bZ bWZT | bWFFAT bWFFBT
// pZ aliases [0,32) (bI..bWV dead after QKV; dead again before bFFA).
// bFFA aliases [0,32). FFB partials alias [32,96) (dead by then).

typedef __bf16 bf16_t;
typedef __bf16 bf16x8 __attribute__((ext_vector_type(8)));
typedef float  f32x4  __attribute__((ext_vector_type(4)));

#define AS1 __attribute__((address_space(1)))
#define AS3 __attribute__((address_space(3)))

__device__ __forceinline__ void load16_lds(const bf16_t* g, bf16_t* l) {
    // 16B per lane, LDS dest = wave-uniform base + lane*16
    __builtin_amdgcn_global_load_lds((AS1 void*)g, (AS3 void*)l, 16, 0, 0);
}

// 16-lane (DPP row) reductions: row_ror 8/4/2/1 butterflies, all-VALU.
__device__ __forceinline__ float rowmax16(float v) {
    int t;
    t = __builtin_amdgcn_mov_dpp(__float_as_int(v), 0x128, 0xf, 0xf, true);
    v = fmaxf(v, __int_as_float(t));
    t = __builtin_amdgcn_mov_dpp(__float_as_int(v), 0x124, 0xf, 0xf, true);
    v = fmaxf(v, __int_as_float(t));
    t = __builtin_amdgcn_mov_dpp(__float_as_int(v), 0x122, 0xf, 0xf, true);
    v = fmaxf(v, __int_as_float(t));
    t = __builtin_amdgcn_mov_dpp(__float_as_int(v), 0x121, 0xf, 0xf, true);
    v = fmaxf(v, __int_as_float(t));
    return v;
}
__device__ __forceinline__ float rowsum16(float v) {
    int t;
    t = __builtin_amdgcn_mov_dpp(__float_as_int(v), 0x128, 0xf, 0xf, true);
    v += __int_as_float(t);
    t = __builtin_amdgcn_mov_dpp(__float_as_int(v), 0x124, 0xf, 0xf, true);
    v += __int_as_float(t);
    t = __builtin_amdgcn_mov_dpp(__float_as_int(v), 0x122, 0xf, 0xf, true);
    v += __int_as_float(t);
    t = __builtin_amdgcn_mov_dpp(__float_as_int(v), 0x121, 0xf, 0xf, true);
    v += __int_as_float(t);
    return v;
}

// ---- half-tile staging (slot = 128 rows x 64 cols, 16KB) ----
// A half h = logical rows {r : (r>>6)&1 == h} (bit6 partition)
// B half h = logical rows {r : (r>>5)&1 == h} (bit5 partition)
// chunk c of phys row p holds logical chunk c ^ (p&7)  (read-side XOR swizzle)
__device__ __forceinline__ void stageA_half(const bf16_t* __restrict__ Ab, int lda,
                                            int k0, int h, bf16_t* slot,
                                            int w, int lane)
{
    #pragma unroll
    for (int j = 0; j < 2; ++j) {
        const int prw = j * 64 + w * 8;          // wave-uniform phys row base
        const int p   = prw + (lane >> 3);
        const int lr  = (p >> 6) * 128 + h * 64 + (p & 63);
        const int lc  = (lane & 7) ^ (p & 7);
        load16_lds(Ab + (long long)lr * lda + k0 + lc * 8, slot + prw * 64);
    }
}
__device__ __forceinline__ void stageB_half(const bf16_t* __restrict__ Bb, int ldb,
                                            int k0, int h, bf16_t* slot,
                                            int w, int lane)
{
    #pragma unroll
    for (int j = 0; j < 2; ++j) {
        const int prw = j * 64 + w * 8;
        const int p   = prw + (lane >> 3);
        const int lr  = (p >> 5) * 64 + h * 32 + (p & 31);
        const int lc  = (lane & 7) ^ (p & 7);
        load16_lds(Bb + (long long)lr * ldb + k0 + lc * 8, slot + prw * 64);
    }
}

#define LOADAF(DST, SL)                                                        \
  _Pragma("unroll") for (int ks = 0; ks < 2; ++ks)                             \
  _Pragma("unroll") for (int mi = 0; mi < 4; ++mi)                             \
      DST[ks][mi] = *(const bf16x8*)&(SL)[(wm * 64 + mi * 16 + c15) * 64 +     \
                      (((ks * 4 + q4) ^ (c15 & 7)) * 8)];

#define LOADBV(DST, SL)                                                        \
  _Pragma("unroll") for (int ks = 0; ks < 2; ++ks)                             \
  _Pragma("unroll") for (int nj = 0; nj < 2; ++nj)                             \
      DST[ks][nj] = *(const bf16x8*)&(SL)[(wn * 32 + nj * 16 + c15) * 64 +     \
                      (((ks * 4 + q4) ^ (c15 & 7)) * 8)];

#define MFMA8(R0, C0)                                                          \
  _Pragma("unroll") for (int ks = 0; ks < 2; ++ks)                             \
  _Pragma("unroll") for (int mi = 0; mi < 4; ++mi)                             \
  _Pragma("unroll") for (int nj = 0; nj < 2; ++nj)                             \
      acc[(R0) + mi][(C0) + nj] = __builtin_amdgcn_mfma_f32_16x16x32_bf16(     \
          af[ks][mi], bv[ks][nj], acc[(R0) + mi][(C0) + nj], 0, 0, 0);

#define VMW(N)  asm volatile("s_waitcnt vmcnt(" #N ")" ::: "memory")
#define LGKM0() asm volatile("s_waitcnt lgkmcnt(0)" ::: "memory")
#define BAR()   __builtin_amdgcn_s_barrier()

// phase: reads -> stage -> [gate] -> barrier -> lgkm(0) -> sched_barrier ->
//        setprio(1) 16xMFMA setprio(0) -> barrier
#define PHASE8(RDS, STGS, GATE, R0, C0)                                        \
  RDS;                                                                         \
  STGS;                                                                        \
  GATE;                                                                        \
  __builtin_amdgcn_s_barrier();                                                \
  asm volatile("s_waitcnt lgkmcnt(0)" ::: "memory");                           \
  __builtin_amdgcn_sched_barrier(0);                                           \
  __builtin_amdgcn_s_setprio(1);                                               \
  MFMA8(R0, C0);                                                               \
  __builtin_amdgcn_s_setprio(0);                                               \
  __builtin_amdgcn_s_barrier();

// ---------------- 256x256 8-phase GEMM (m201 schedule) ----------------
// C = A * B^T: A [M,K] lda, B [N,K] ldb, C [M,N] ldc. 512 thr = 8 waves
// (2M x 4N), per-wave C 128x64, BK=64 in A/B halves. Requires NT even, >=4.
template<typename TOUT>
__global__ __launch_bounds__(512, 2)
void gemm256p_bt(const bf16_t* __restrict__ A, const bf16_t* __restrict__ B,
                 TOUT* __restrict__ Cc, int Kdim,
                 int lda, int ldb, int ldc,
                 long long ab, long long bb, long long cb,
                 int ct_z, bf16_t* __restrict__ ctc, int ldct)
{
    __shared__ __attribute__((aligned(16))) bf16_t As4[4][128 * 64];
    __shared__ __attribute__((aligned(16))) bf16_t Bs4[4][128 * 64];

    const int z = blockIdx.z;
    A  += (long long)z * ab;
    B  += (long long)z * bb;
    Cc += (long long)z * cb;

    const int bm = blockIdx.y * 256;
    const int bn = blockIdx.x * 256;
    const int t = threadIdx.x, lane = t & 63, w = t >> 6;
    const int wm = w >> 2, wn = w & 3;
    const int q4 = lane >> 4, c15 = lane & 15;

    const bf16_t* Ab = A + (long long)bm * lda;
    const bf16_t* Bb = B + (long long)bn * ldb;

    f32x4  acc[8][4] = {};
    bf16x8 af[2][4];   // one A fragment set
    bf16x8 bv[2][2];   // one B fragment set

    // prologue: B0(0) A1(0) A0(0) B1(0) B0(1) A1(1)  (12 loads)
    stageB_half(Bb, ldb, 0,  0, Bs4[0], w, lane);
    stageA_half(Ab, lda, 0,  1, As4[1], w, lane);
    stageA_half(Ab, lda, 0,  0, As4[0], w, lane);
    stageB_half(Bb, ldb, 0,  1, Bs4[1], w, lane);
    stageB_half(Bb, ldb, 64, 0, Bs4[2], w, lane);
    stageA_half(Ab, lda, 64, 1, As4[3], w, lane);
    VMW(4);
    BAR();

    const int NT = Kdim >> 6;          // even, >= 4
    const int kcap = (NT - 1) << 6;

    for (int i = 0; i < NT / 2; ++i) {
        const int u  = 2 * i;
        const int k1 = (u + 1) << 6;
        int k2 = (u + 2) << 6; if (k2 > kcap) k2 = kcap;
        int k3 = (u + 3) << 6; if (k3 > kcap) k3 = kcap;
        PHASE8( LOADAF(af, As4[0]); LOADBV(bv, Bs4[0]),
                stageA_half(Ab, lda, k1, 0, As4[2], w, lane), ((void)0), 0, 0)
        PHASE8( LOADAF(af, As4[1]),
                stageB_half(Bb, ldb, k1, 1, Bs4[3], w, lane), ((void)0), 4, 0)
        PHASE8( LOADBV(bv, Bs4[1]),
                stageB_half(Bb, ldb, k2, 0, Bs4[0], w, lane), ((void)0), 4, 2)
        PHASE8( LOADAF(af, As4[0]),
                stageA_half(Ab, lda, k2, 1, As4[1], w, lane), VMW(4), 0, 2)
        PHASE8( LOADAF(af, As4[2]); LOADBV(bv, Bs4[2]),
                stageA_half(Ab, lda, k2, 0, As4[0], w, lane), ((void)0), 0, 0)
        PHASE8( LOADAF(af, As4[3]),
                stageB_half(Bb, ldb, k2, 1, Bs4[1], w, lane), ((void)0), 4, 0)
        PHASE8( LOADBV(bv, Bs4[3]),
                stageB_half(Bb, ldb, k3, 0, Bs4[2], w, lane), ((void)0), 4, 2)
        PHASE8( LOADAF(af, As4[2]),
                stageA_half(Ab, lda, k3, 1, As4[3], w, lane), VMW(4), 0, 2)
    }
    VMW(0);   // drain tail junk stages before exit

    // ---- epilogue. C/D layout: col = lane&15, row = (lane>>4)*4 + reg ----
    const int rb = q4 * 4;
    if (z == ct_z) {
        #pragma unroll
        for (int mi = 0; mi < 8; ++mi) {
            const long long mb = bm + wm * 128 + mi * 16 + rb;
            #pragma unroll
            for (int nj = 0; nj < 4; ++nj) {
                const long long n = bn + wn * 64 + nj * 16 + c15;
                union { bf16_t b[4]; unsigned long long u; } o;
                #pragma unroll
                for (int r = 0; r < 4; ++r) o.b[r] = (bf16_t)acc[mi][nj][r];
                *(unsigned long long*)(ctc + n * ldct + mb) = o.u;
            }
        }
    } else {
        #pragma unroll
        for (int mi = 0; mi < 8; ++mi) {
            #pragma unroll
            for (int r = 0; r < 4; ++r) {
                const long long m = bm + wm * 128 + mi * 16 + rb + r;
                TOUT* crow = Cc + m * ldc + bn + wn * 64 + c15;
                #pragma unroll
                for (int nj = 0; nj < 4; ++nj)
                    crow[nj * 16] = (TOUT)acc[mi][nj][r];
            }
        }
    }
}

// ---------------- flash attention v3 (dbuf + DPP softmax + defer-max) ------
// Grid (M/64, H). Block 256 = 4 waves; wave owns 16 q-rows. KV tile = 64.
// Per iter: issue stage(t+1) -> VMW(8) BAR -> QK^T -> softmax (DPP reduces,
// defer-max THR=8, P same-wave so lgkm only) -> PV -> BAR.
__global__ __launch_bounds__(256, 2)
void flash_attn(const bf16_t* __restrict__ Q, const bf16_t* __restrict__ K,
                const bf16_t* __restrict__ VT, bf16_t* __restrict__ O,
                int M, int D)
{
    __shared__ bf16_t Kt[2][64 * 128];
    __shared__ bf16_t Vt[2][128 * 64];
    __shared__ bf16_t Pl[4 * 16 * 88];

    const int t = threadIdx.x, lane = t & 63, w = t >> 6;
    const int q4 = lane >> 4;
    const int c  = lane & 15;
    const int bm = blockIdx.x * 64;
    const int hE = blockIdx.y * 128;

    bf16x8 af_q[4];
    {
        const bf16_t* qrow = Q + (long long)(bm + w * 16 + c) * D + hE + q4 * 8;
        #pragma unroll
        for (int ks = 0; ks < 4; ++ks)
            af_q[ks] = *(const bf16x8*)(qrow + ks * 32);
    }

    f32x4 acc_o[8] = {};
    float m_i[4] = {-INFINITY, -INFINITY, -INFINITY, -INFINITY};
    float l_i[4] = {0.f, 0.f, 0.f, 0.f};

    bf16_t* Pw = &Pl[w * 16 * 88];

    const int NT = M >> 6;     // 32

    // stage K/V tile at row-offset p0 into buffer b (8 loads/wave)
    #define FA_STAGE(P0, B)                                                    \
      _Pragma("unroll")                                                        \
      for (int j = 0; j < 4; ++j) {                                            \
          int krow = w * 16 + j * 4;                                           \
          load16_lds(K + (long long)((P0) + krow + q4) * D + hE +              \
                         ((c ^ (j * 4 + q4)) * 8),                             \
                     &Kt[B][krow * 128]);                                      \
          int vrow = w * 32 + j * 8;                                           \
          load16_lds(VT + (long long)(hE + vrow + (lane >> 3)) * M + (P0) +    \
                         (((lane & 7) ^ (lane >> 3)) * 8),                     \
                     &Vt[B][vrow * 64]);                                       \
      }

    FA_STAGE(0, 0)

    for (int ti = 0; ti < NT; ++ti) {
        const int cur = ti & 1;
        // issue next tile's loads (tail: restage current tile into dead buf)
        const int pn = (ti + 1 < NT) ? (ti + 1) * 64 : ti * 64;
        FA_STAGE(pn, cur ^ 1)
        VMW(8);            // retire tile ti's 8 loads (issued one iter ago)
        BAR();             // all waves' contributions to Kt/Vt[cur] visible

        // ---- S = Q K^T : wave computes [16, 64] ----
        f32x4 acc_s[4] = {};
        __builtin_amdgcn_s_setprio(1);
        #pragma unroll
        for (int ks = 0; ks < 4; ++ks) {
            #pragma unroll
            for (int nj = 0; nj < 4; ++nj) {
                int row = nj * 16 + c;
                bf16x8 bk = *(const bf16x8*)&Kt[cur][row * 128 + (((ks * 4 + q4) ^ c) * 8)];
                acc_s[nj] = __builtin_amdgcn_mfma_f32_16x16x32_bf16(
                    af_q[ks], bk, acc_s[nj], 0, 0, 0);
            }
        }
        __builtin_amdgcn_s_setprio(0);

        // ---- online softmax: DPP row-reduce + defer-max (THR=8) ----
        float mt[4], rs[4];
        #pragma unroll
        for (int r = 0; r < 4; ++r) {
            mt[r] = rowmax16(fmaxf(fmaxf(acc_s[0][r], acc_s[1][r]),
                                   fmaxf(acc_s[2][r], acc_s[3][r])));
            rs[r] = 0.f;
        }
        bool ok = true;
        #pragma unroll
        for (int r = 0; r < 4; ++r) ok = ok && (mt[r] <= m_i[r] + 8.0f);
        if (__all(ok)) {
            // light path: keep m_i, P bounded by e^8, no O-rescale
            #pragma unroll
            for (int nj = 0; nj < 4; ++nj)
                #pragma unroll
                for (int r = 0; r < 4; ++r) {
                    float p = __expf(acc_s[nj][r] - m_i[r]);
                    rs[r] += p;
                    Pw[(q4 * 4 + r) * 88 + nj * 16 + c] = (bf16_t)p;
                }
            #pragma unroll
            for (int r = 0; r < 4; ++r)
                l_i[r] += rowsum16(rs[r]);
        } else {
            float alpha[4];
            #pragma unroll
            for (int r = 0; r < 4; ++r) {
                float mn = fmaxf(m_i[r], mt[r]);
                alpha[r] = __expf(m_i[r] - mn);
                m_i[r] = mn;
            }
            #pragma unroll
            for (int nj = 0; nj < 4; ++nj)
                #pragma unroll
                for (int r = 0; r < 4; ++r) {
                    float p = __expf(acc_s[nj][r] - m_i[r]);
                    rs[r] += p;
                    Pw[(q4 * 4 + r) * 88 + nj * 16 + c] = (bf16_t)p;
                }
            #pragma unroll
            for (int r = 0; r < 4; ++r)
                l_i[r] = alpha[r] * l_i[r] + rowsum16(rs[r]);
            #pragma unroll
            for (int nj = 0; nj < 8; ++nj)
                #pragma unroll
                for (int r = 0; r < 4; ++r)
                    acc_o[nj][r] *= alpha[r];
        }

        // P store -> read is same-wave: lgkm wait only, no barrier
        LGKM0();
        __builtin_amdgcn_sched_barrier(0);

        // ---- O += P V : A = P [m][p], B = Vt [e][p] ----
        __builtin_amdgcn_s_setprio(1);
        #pragma unroll
        for (int ks = 0; ks < 2; ++ks) {
            bf16x8 ap = *(const bf16x8*)&Pw[c * 88 + ks * 32 + q4 * 8];
            #pragma unroll
            for (int nj = 0; nj < 8; ++nj) {
                int row = nj * 16 + c;
                bf16x8 bvv = *(const bf16x8*)&Vt[cur][row * 64 + (((ks * 4 + q4) ^ (c & 7)) * 8)];
                acc_o[nj] = __builtin_amdgcn_mfma_f32_16x16x32_bf16(
                    ap, bvv, acc_o[nj], 0, 0, 0);
            }
        }
        __builtin_amdgcn_s_setprio(0);
        BAR();             // all reads of buf[cur] done before next overwrite
    }
    VMW(0);                // drain tail junk stages before LDS goes away

    float inv[4];
    #pragma unroll
    for (int r = 0; r < 4; ++r) inv[r] = 1.0f / l_i[r];
    #pragma unroll
    for (int nj = 0; nj < 8; ++nj)
        #pragma unroll
        for (int r = 0; r < 4; ++r)
            O[(long long)(bm + w * 16 + q4 * 4 + r) * D + hE + nj * 16 + c] =
                (bf16_t)(acc_o[nj][r] * inv[r]);
    #undef FA_STAGE
}

// ---------------- small utility kernels ----------------
__global__ __launch_bounds__(256)
void cast4_bf16(const float* __restrict__ s0, const float* __restrict__ s1,
                const float* __restrict__ s2, const float* __restrict__ s3,
                bf16_t* __restrict__ d0, long long seg, long long n)
{
    const float* src = (blockIdx.y == 0) ? s0 : (blockIdx.y == 1) ? s1
                     : (blockIdx.y == 2) ? s2 : s3;
    bf16_t* dst = d0 + (long long)blockIdx.y * seg;
    long long i = ((long long)blockIdx.x * 256 + threadIdx.x) * 4;
    if (i >= n) return;
    float4 v = *(const float4*)(src + i);
    union { bf16_t b[4]; unsigned long long u; } o;
    o.b[0] = (bf16_t)v.x; o.b[1] = (bf16_t)v.y;
    o.b[2] = (bf16_t)v.z; o.b[3] = (bf16_t)v.w;
    *(unsigned long long*)(dst + i) = o.u;
}

__global__ __launch_bounds__(256)
void transpose_to_bf16(const float* __restrict__ in, bf16_t* __restrict__ out,
                       int rows, int cols)
{
    __shared__ bf16_t tile[32][33];
    const int r0 = blockIdx.y * 32, c0 = blockIdx.x * 32;
    const int tx = threadIdx.x & 31, ty = threadIdx.x >> 5;
    #pragma unroll
    for (int i = 0; i < 4; ++i) {
        int r = ty + i * 8;
        tile[r][tx] = (bf16_t)in[(long long)(r0 + r) * cols + c0 + tx];
    }
    __syncthreads();
    #pragma unroll
    for (int i = 0; i < 4; ++i) {
        int r = ty + i * 8;
        out[(long long)(c0 + r) * rows + r0 + tx] = tile[tx][r];
    }
}

__global__ __launch_bounds__(256)
void reduce4_f32(const float* __restrict__ p, float* __restrict__ out,
                 long long n)
{
    long long i = ((long long)blockIdx.x * 256 + threadIdx.x) * 4;
    if (i >= n) return;
    float4 a = *(const float4*)(p + i);
    float4 b = *(const float4*)(p + n + i);
    float4 c = *(const float4*)(p + 2 * n + i);
    float4 d = *(const float4*)(p + 3 * n + i);
    float4 o;
    o.x = a.x + b.x + c.x + d.x;
    o.y = a.y + b.y + c.y + d.y;
    o.z = a.z + b.z + c.z + d.z;
    o.w = a.w + b.w + c.w + d.w;
    *(float4*)(out + i) = o;
}

__global__ __launch_bounds__(256)
void reduce2_bf16(const float* __restrict__ p, bf16_t* __restrict__ out,
                  long long n)
{
    long long i = ((long long)blockIdx.x * 256 + threadIdx.x) * 4;
    if (i >= n) return;
    float4 a = *(const float4*)(p + i);
    float4 b = *(const float4*)(p + n + i);
    union { bf16_t b[4]; unsigned long long u; } o;
    o.b[0] = (bf16_t)(a.x + b.x);
    o.b[1] = (bf16_t)(a.y + b.y);
    o.b[2] = (bf16_t)(a.z + b.z);
    o.b[3] = (bf16_t)(a.w + b.w);
    *(unsigned long long*)(out + i) = o.u;
}

extern "C" void kernel_launch(void* const* d_in, const int* in_sizes, int n_in,
                              void* d_out, int out_size, void* d_ws, size_t ws_size,
                              hipStream_t stream)
{
    const float* I    = (const float*)d_in[0];
    const float* WV   = (const float*)d_in[1];
    const float* WK   = (const float*)d_in[2];
    const float* WQ   = (const float*)d_in[3];
    const float* WZ   = (const float*)d_in[4];
    const float* WFFA = (const float*)d_in[5];
    const float* WFFB = (const float*)d_in[6];
    float* out = (float*)d_out;                  // [M, D] fp32

    const int M = 2048, D = 2048, C = 8192;
    const long long MD = (long long)M * D;
    const size_t MiB = 1024 * 1024;

    char* base = (char*)d_ws;
    bf16_t* bI     = (bf16_t*)(base + 0 * MiB);
    bf16_t* bWQ    = (bf16_t*)(base + 8 * MiB);    // contiguous WQ,WK,WV (z-batch)
    bf16_t* bWK    = (bf16_t*)(base + 16 * MiB);
    bf16_t* bWV    = (bf16_t*)(base + 24 * MiB);
    bf16_t* bQ     = (bf16_t*)(base + 32 * MiB);   // contiguous Q,K (z-batch out)
    bf16_t* bK     = (bf16_t*)(base + 40 * MiB);
    bf16_t* bVT    = (bf16_t*)(base + 48 * MiB);   // [D, M] via ct_z epilogue
    bf16_t* bAV    = (bf16_t*)(base + 56 * MiB);
    bf16_t* bZ     = (bf16_t*)(base + 64 * MiB);
    bf16_t* bWZT   = (bf16_t*)(base + 72 * MiB);
    bf16_t* bWFFAT = (bf16_t*)(base + 80 * MiB);   // [C, D]
    bf16_t* bWFFBT = (bf16_t*)(base + 112 * MiB);  // [D, C]
    bf16_t* bFFA   = (bf16_t*)(base + 0 * MiB);    // [M, C] bf16 (bI..bWV dead)
    float*  pZ     = (float*)(base + 0 * MiB);     // 2x [M,D] fp32 Z partials
    float*  pF     = (float*)(base + 32 * MiB);    // 4x [M,D] fp32 FFB partials

    const dim3 blk(256);
    const dim3 blk512(512);

    // ---- prep: casts + weight transposes ----
    cast4_bf16<<<dim3(MD / 1024, 4), blk, 0, stream>>>(I, WQ, WK, WV, bI, MD, MD);
    transpose_to_bf16<<<dim3(D / 32, D / 32), blk, 0, stream>>>(WZ,   bWZT,   D, D);
    transpose_to_bf16<<<dim3(C / 32, D / 32), blk, 0, stream>>>(WFFA, bWFFAT, D, C);
    transpose_to_bf16<<<dim3(D / 32, C / 32), blk, 0, stream>>>(WFFB, bWFFBT, C, D);

    // ---- QKV in one z=3 dispatch; V -> bVT transposed ----
    gemm256p_bt<bf16_t><<<dim3(8, 8, 3), blk512, 0, stream>>>(
        bI, bWQ, bQ, D, D, D, D, 0, MD, MD, /*ct_z=*/2, bVT, M);

    // ---- flash attention: Q,K,VT -> AV ----
    flash_attn<<<dim3(M / 64, 16), blk, 0, stream>>>(bQ, bK, bVT, bAV, M, D);

    // ---- Z = AV x WZ^T, split-K=2 -> fp32 partials + reduce to bf16 ----
    gemm256p_bt<float><<<dim3(8, 8, 2), blk512, 0, stream>>>(
        bAV, bWZT, pZ, 1024, D, D, D, 1024, 1024, MD, -1, nullptr, 0);
    reduce2_bf16<<<dim3((int)(MD / 1024)), blk, 0, stream>>>(pZ, bZ, MD);

    // ---- FFA = Z x WFFA^T ----
    gemm256p_bt<bf16_t><<<dim3(32, 8, 1), blk512, 0, stream>>>(
        bZ, bWFFAT, bFFA, D, D, D, C, 0, 0, 0, -1, nullptr, 0);

    // ---- FFB = FFA x WFFB^T, split-K=4 -> fp32 partials (plain stores) ----
    gemm256p_bt<float><<<dim3(8, 8, 4), blk512, 0, stream>>>(
        bFFA, bWFFBT, pF, 2048, C, C, D, 2048, 2048, MD, -1, nullptr, 0);

    // ---- out = sum of 4 partials ----
    reduce4_f32<<<dim3((int)(MD / 1024)), blk, 0, stream>>>(pF, out, MD);
}

// Round 7
// 564.401 us; speedup vs baseline: 1.6094x; 1.0262x over previous
//
#include <hip/hip_runtime.h>
#include <hip/hip_bf16.h>
#include <math.h>

// GPT3 block on MI355X, round 12:
//  - gemm256p_bt v2: ds_read diet 32->24 b128/K-tile/wave (quadrant order
//    (0,0)(0,1)(1,1)(1,0), hold bv0+bv1 sets; reads 12/4/8/0 per phase).
//    Round-11 counters: 6287 cyc/K-tile, LDS pipe 768 cyc/phase > MFMA 516
//    -> LDS-read bound. Staging slots/vmcnt gates identical to verified r11.
//  - XCD chunked swizzle (T1) on gemm256p + flash_attn (all grids %8==0):
//    A-panel / head K,V locality per XCD L2 (FFB FETCH 147MB vs 64 unique).
//  - flash_attn v3 (DPP softmax + defer-max + dbuf) otherwise unchanged.
//  - FFB split-K=4 -> fp32 partials + reduce4; Z split-K=2 + reduce2.
// ws 144 MiB: bI bWQ bWK bWV | bQ bK bVT bAV bZ bWZT | bWFFAT bWFFBT
// pZ aliases [0,32) (bI..bWV dead). bFFA aliases [0,32). pF [32,96).

typedef __bf16 bf16_t;
typedef __bf16 bf16x8 __attribute__((ext_vector_type(8)));
typedef float  f32x4  __attribute__((ext_vector_type(4)));

#define AS1 __attribute__((address_space(1)))
#define AS3 __attribute__((address_space(3)))

__device__ __forceinline__ void load16_lds(const bf16_t* g, bf16_t* l) {
    // 16B per lane, LDS dest = wave-uniform base + lane*16
    __builtin_amdgcn_global_load_lds((AS1 void*)g, (AS3 void*)l, 16, 0, 0);
}

// 16-lane (DPP row) reductions: row_ror 8/4/2/1 butterflies, all-VALU.
__device__ __forceinline__ float rowmax16(float v) {
    int t;
    t = __builtin_amdgcn_mov_dpp(__float_as_int(v), 0x128, 0xf, 0xf, true);
    v = fmaxf(v, __int_as_float(t));
    t = __builtin_amdgcn_mov_dpp(__float_as_int(v), 0x124, 0xf, 0xf, true);
    v = fmaxf(v, __int_as_float(t));
    t = __builtin_amdgcn_mov_dpp(__float_as_int(v), 0x122, 0xf, 0xf, true);
    v = fmaxf(v, __int_as_float(t));
    t = __builtin_amdgcn_mov_dpp(__float_as_int(v), 0x121, 0xf, 0xf, true);
    v = fmaxf(v, __int_as_float(t));
    return v;
}
__device__ __forceinline__ float rowsum16(float v) {
    int t;
    t = __builtin_amdgcn_mov_dpp(__float_as_int(v), 0x128, 0xf, 0xf, true);
    v += __int_as_float(t);
    t = __builtin_amdgcn_mov_dpp(__float_as_int(v), 0x124, 0xf, 0xf, true);
    v += __int_as_float(t);
    t = __builtin_amdgcn_mov_dpp(__float_as_int(v), 0x122, 0xf, 0xf, true);
    v += __int_as_float(t);
    t = __builtin_amdgcn_mov_dpp(__float_as_int(v), 0x121, 0xf, 0xf, true);
    v += __int_as_float(t);
    return v;
}

// ---- half-tile staging (slot = 128 rows x 64 cols, 16KB) ----
// A half h = logical rows {r : (r>>6)&1 == h} (bit6 partition)
// B half h = logical rows {r : (r>>5)&1 == h} (bit5 partition)
// chunk c of phys row p holds logical chunk c ^ (p&7)  (read-side XOR swizzle)
__device__ __forceinline__ void stageA_half(const bf16_t* __restrict__ Ab, int lda,
                                            int k0, int h, bf16_t* slot,
                                            int w, int lane)
{
    #pragma unroll
    for (int j = 0; j < 2; ++j) {
        const int prw = j * 64 + w * 8;          // wave-uniform phys row base
        const int p   = prw + (lane >> 3);
        const int lr  = (p >> 6) * 128 + h * 64 + (p & 63);
        const int lc  = (lane & 7) ^ (p & 7);
        load16_lds(Ab + (long long)lr * lda + k0 + lc * 8, slot + prw * 64);
    }
}
__device__ __forceinline__ void stageB_half(const bf16_t* __restrict__ Bb, int ldb,
                                            int k0, int h, bf16_t* slot,
                                            int w, int lane)
{
    #pragma unroll
    for (int j = 0; j < 2; ++j) {
        const int prw = j * 64 + w * 8;
        const int p   = prw + (lane >> 3);
        const int lr  = (p >> 5) * 64 + h * 32 + (p & 31);
        const int lc  = (lane & 7) ^ (p & 7);
        load16_lds(Bb + (long long)lr * ldb + k0 + lc * 8, slot + prw * 64);
    }
}

#define LOADAF(DST, SL)                                                        \
  _Pragma("unroll") for (int ks = 0; ks < 2; ++ks)                             \
  _Pragma("unroll") for (int mi = 0; mi < 4; ++mi)                             \
      DST[ks][mi] = *(const bf16x8*)&(SL)[(wm * 64 + mi * 16 + c15) * 64 +     \
                      (((ks * 4 + q4) ^ (c15 & 7)) * 8)];

#define LOADBV(DST, SL)                                                        \
  _Pragma("unroll") for (int ks = 0; ks < 2; ++ks)                             \
  _Pragma("unroll") for (int nj = 0; nj < 2; ++nj)                             \
      DST[ks][nj] = *(const bf16x8*)&(SL)[(wn * 32 + nj * 16 + c15) * 64 +     \
                      (((ks * 4 + q4) ^ (c15 & 7)) * 8)];

#define MFMA8(R0, C0, BV)                                                      \
  _Pragma("unroll") for (int ks = 0; ks < 2; ++ks)                             \
  _Pragma("unroll") for (int mi = 0; mi < 4; ++mi)                             \
  _Pragma("unroll") for (int nj = 0; nj < 2; ++nj)                             \
      acc[(R0) + mi][(C0) + nj] = __builtin_amdgcn_mfma_f32_16x16x32_bf16(     \
          af[ks][mi], BV[ks][nj], acc[(R0) + mi][(C0) + nj], 0, 0, 0);

#define VMW(N)  asm volatile("s_waitcnt vmcnt(" #N ")" ::: "memory")
#define LGKM0() asm volatile("s_waitcnt lgkmcnt(0)" ::: "memory")
#define BAR()   __builtin_amdgcn_s_barrier()

// phase: reads -> stage -> [gate] -> barrier -> lgkm(0) -> sched_barrier ->
//        setprio(1) 16xMFMA setprio(0) -> barrier
#define PHASE8(RDS, STGS, GATE, R0, C0, BV)                                    \
  RDS;                                                                         \
  STGS;                                                                        \
  GATE;                                                                        \
  __builtin_amdgcn_s_barrier();                                                \
  asm volatile("s_waitcnt lgkmcnt(0)" ::: "memory");                           \
  __builtin_amdgcn_sched_barrier(0);                                           \
  __builtin_amdgcn_s_setprio(1);                                               \
  MFMA8(R0, C0, BV);                                                           \
  __builtin_amdgcn_s_setprio(0);                                               \
  __builtin_amdgcn_s_barrier();

// ---------------- 256x256 8-phase GEMM (m201 schedule, read-diet) ----------
// C = A * B^T: A [M,K] lda, B [N,K] ldb, C [M,N] ldc. 512 thr = 8 waves
// (2M x 4N), per-wave C 128x64, BK=64 in A/B halves. Requires NT even, >=4.
// Grid linearized + XCD-chunk-swizzled (requires nwg % 8 == 0).
template<typename TOUT>
__global__ __launch_bounds__(512, 2)
void gemm256p_bt(const bf16_t* __restrict__ A, const bf16_t* __restrict__ B,
                 TOUT* __restrict__ Cc, int Kdim,
                 int lda, int ldb, int ldc,
                 long long ab, long long bb, long long cb,
                 int ct_z, bf16_t* __restrict__ ctc, int ldct)
{
    __shared__ __attribute__((aligned(16))) bf16_t As4[4][128 * 64];
    __shared__ __attribute__((aligned(16))) bf16_t Bs4[4][128 * 64];

    // XCD chunked swizzle: XCD k gets a contiguous chunk of logical tiles
    // (consecutive x first -> A-panel reuse within the XCD's L2).
    const int nx = gridDim.x, ny = gridDim.y;
    const int nwg = nx * ny * gridDim.z;
    const int flat = blockIdx.x + nx * (blockIdx.y + ny * blockIdx.z);
    const int cpx = nwg >> 3;
    const int swz = (flat & 7) * cpx + (flat >> 3);
    const int bx = swz % nx;
    const int tmp = swz / nx;
    const int by = tmp % ny;
    const int z  = tmp / ny;

    A  += (long long)z * ab;
    B  += (long long)z * bb;
    Cc += (long long)z * cb;

    const int bm = by * 256;
    const int bn = bx * 256;
    const int t = threadIdx.x, lane = t & 63, w = t >> 6;
    const int wm = w >> 2, wn = w & 3;
    const int q4 = lane >> 4, c15 = lane & 15;

    const bf16_t* Ab = A + (long long)bm * lda;
    const bf16_t* Bb = B + (long long)bn * ldb;

    f32x4  acc[8][4] = {};
    bf16x8 af[2][4];    // A fragment set (A0 in ph1-2, A1 in ph3-4)
    bf16x8 bv0[2][2];   // B half0 frags (live ph1..ph4)
    bf16x8 bv1[2][2];   // B half1 frags (live ph2..ph3)

    // prologue: B0(0) A1(0) A0(0) B1(0) B0(1) A1(1)  (12 loads)
    stageB_half(Bb, ldb, 0,  0, Bs4[0], w, lane);
    stageA_half(Ab, lda, 0,  1, As4[1], w, lane);
    stageA_half(Ab, lda, 0,  0, As4[0], w, lane);
    stageB_half(Bb, ldb, 0,  1, Bs4[1], w, lane);
    stageB_half(Bb, ldb, 64, 0, Bs4[2], w, lane);
    stageA_half(Ab, lda, 64, 1, As4[3], w, lane);
    VMW(4);
    BAR();

    const int NT = Kdim >> 6;          // even, >= 4
    const int kcap = (NT - 1) << 6;

    for (int i = 0; i < NT / 2; ++i) {
        const int u  = 2 * i;
        const int k1 = (u + 1) << 6;
        int k2 = (u + 2) << 6; if (k2 > kcap) k2 = kcap;
        int k3 = (u + 3) << 6; if (k3 > kcap) k3 = kcap;
        // tile u (slots 0/1): quadrants (0,0)(0,1)(1,1)(1,0), reads 12/4/8/0
        PHASE8( LOADAF(af, As4[0]); LOADBV(bv0, Bs4[0]),
                stageA_half(Ab, lda, k1, 0, As4[2], w, lane), ((void)0), 0, 0, bv0)
        PHASE8( LOADBV(bv1, Bs4[1]),
                stageB_half(Bb, ldb, k1, 1, Bs4[3], w, lane), ((void)0), 0, 2, bv1)
        PHASE8( LOADAF(af, As4[1]),
                stageB_half(Bb, ldb, k2, 0, Bs4[0], w, lane), ((void)0), 4, 2, bv1)
        PHASE8( ((void)0),
                stageA_half(Ab, lda, k2, 1, As4[1], w, lane), VMW(4), 4, 0, bv0)
        // tile u+1 (slots 2/3)
        PHASE8( LOADAF(af, As4[2]); LOADBV(bv0, Bs4[2]),
                stageA_half(Ab, lda, k2, 0, As4[0], w, lane), ((void)0), 0, 0, bv0)
        PHASE8( LOADBV(bv1, Bs4[3]),
                stageB_half(Bb, ldb, k2, 1, Bs4[1], w, lane), ((void)0), 0, 2, bv1)
        PHASE8( LOADAF(af, As4[3]),
                stageB_half(Bb, ldb, k3, 0, Bs4[2], w, lane), ((void)0), 4, 2, bv1)
        PHASE8( ((void)0),
                stageA_half(Ab, lda, k3, 1, As4[3], w, lane), VMW(4), 4, 0, bv0)
    }
    VMW(0);   // drain tail junk stages before exit

    // ---- epilogue. C/D layout: col = lane&15, row = (lane>>4)*4 + reg ----
    const int rb = q4 * 4;
    if (z == ct_z) {
        #pragma unroll
        for (int mi = 0; mi < 8; ++mi) {
            const long long mb = bm + wm * 128 + mi * 16 + rb;
            #pragma unroll
            for (int nj = 0; nj < 4; ++nj) {
                const long long n = bn + wn * 64 + nj * 16 + c15;
                union { bf16_t b[4]; unsigned long long u; } o;
                #pragma unroll
                for (int r = 0; r < 4; ++r) o.b[r] = (bf16_t)acc[mi][nj][r];
                *(unsigned long long*)(ctc + n * ldct + mb) = o.u;
            }
        }
    } else {
        #pragma unroll
        for (int mi = 0; mi < 8; ++mi) {
            #pragma unroll
            for (int r = 0; r < 4; ++r) {
                const long long m = bm + wm * 128 + mi * 16 + rb + r;
                TOUT* crow = Cc + m * ldc + bn + wn * 64 + c15;
                #pragma unroll
                for (int nj = 0; nj < 4; ++nj)
                    crow[nj * 16] = (TOUT)acc[mi][nj][r];
            }
        }
    }
}

// ---------------- flash attention v3 (dbuf + DPP softmax + defer-max) ------
// Grid (M/64 x H) linearized + XCD-chunk swizzle (each XCD gets ~2 heads).
// Block 256 = 4 waves; wave owns 16 q-rows. KV tile = 64.
__global__ __launch_bounds__(256, 2)
void flash_attn(const bf16_t* __restrict__ Q, const bf16_t* __restrict__ K,
                const bf16_t* __restrict__ VT, bf16_t* __restrict__ O,
                int M, int D)
{
    __shared__ bf16_t Kt[2][64 * 128];
    __shared__ bf16_t Vt[2][128 * 64];
    __shared__ bf16_t Pl[4 * 16 * 88];

    const int t = threadIdx.x, lane = t & 63, w = t >> 6;
    const int q4 = lane >> 4;
    const int c  = lane & 15;

    const int nwg = gridDim.x * gridDim.y;
    const int flat = blockIdx.x + gridDim.x * blockIdx.y;
    const int cpx = nwg >> 3;
    const int swz = (flat & 7) * cpx + (flat >> 3);
    const int bm = (swz % gridDim.x) * 64;
    const int hE = (swz / gridDim.x) * 128;

    bf16x8 af_q[4];
    {
        const bf16_t* qrow = Q + (long long)(bm + w * 16 + c) * D + hE + q4 * 8;
        #pragma unroll
        for (int ks = 0; ks < 4; ++ks)
            af_q[ks] = *(const bf16x8*)(qrow + ks * 32);
    }

    f32x4 acc_o[8] = {};
    float m_i[4] = {-INFINITY, -INFINITY, -INFINITY, -INFINITY};
    float l_i[4] = {0.f, 0.f, 0.f, 0.f};

    bf16_t* Pw = &Pl[w * 16 * 88];

    const int NT = M >> 6;     // 32

    // stage K/V tile at row-offset p0 into buffer b (8 loads/wave)
    #define FA_STAGE(P0, B)                                                    \
      _Pragma("unroll")                                                        \
      for (int j = 0; j < 4; ++j) {                                            \
          int krow = w * 16 + j * 4;                                           \
          load16_lds(K + (long long)((P0) + krow + q4) * D + hE +              \
                         ((c ^ (j * 4 + q4)) * 8),                             \
                     &Kt[B][krow * 128]);                                      \
          int vrow = w * 32 + j * 8;                                           \
          load16_lds(VT + (long long)(hE + vrow + (lane >> 3)) * M + (P0) +    \
                         (((lane & 7) ^ (lane >> 3)) * 8),                     \
                     &Vt[B][vrow * 64]);                                       \
      }

    FA_STAGE(0, 0)

    for (int ti = 0; ti < NT; ++ti) {
        const int cur = ti & 1;
        // issue next tile's loads (tail: restage current tile into dead buf)
        const int pn = (ti + 1 < NT) ? (ti + 1) * 64 : ti * 64;
        FA_STAGE(pn, cur ^ 1)
        VMW(8);            // retire tile ti's 8 loads (issued one iter ago)
        BAR();             // all waves' contributions to Kt/Vt[cur] visible

        // ---- S = Q K^T : wave computes [16, 64] ----
        f32x4 acc_s[4] = {};
        __builtin_amdgcn_s_setprio(1);
        #pragma unroll
        for (int ks = 0; ks < 4; ++ks) {
            #pragma unroll
            for (int nj = 0; nj < 4; ++nj) {
                int row = nj * 16 + c;
                bf16x8 bk = *(const bf16x8*)&Kt[cur][row * 128 + (((ks * 4 + q4) ^ c) * 8)];
                acc_s[nj] = __builtin_amdgcn_mfma_f32_16x16x32_bf16(
                    af_q[ks], bk, acc_s[nj], 0, 0, 0);
            }
        }
        __builtin_amdgcn_s_setprio(0);

        // ---- online softmax: DPP row-reduce + defer-max (THR=8) ----
        float mt[4], rs[4];
        #pragma unroll
        for (int r = 0; r < 4; ++r) {
            mt[r] = rowmax16(fmaxf(fmaxf(acc_s[0][r], acc_s[1][r]),
                                   fmaxf(acc_s[2][r], acc_s[3][r])));
            rs[r] = 0.f;
        }
        bool ok = true;
        #pragma unroll
        for (int r = 0; r < 4; ++r) ok = ok && (mt[r] <= m_i[r] + 8.0f);
        if (__all(ok)) {
            // light path: keep m_i, P bounded by e^8, no O-rescale
            #pragma unroll
            for (int nj = 0; nj < 4; ++nj)
                #pragma unroll
                for (int r = 0; r < 4; ++r) {
                    float p = __expf(acc_s[nj][r] - m_i[r]);
                    rs[r] += p;
                    Pw[(q4 * 4 + r) * 88 + nj * 16 + c] = (bf16_t)p;
                }
            #pragma unroll
            for (int r = 0; r < 4; ++r)
                l_i[r] += rowsum16(rs[r]);
        } else {
            float alpha[4];
            #pragma unroll
            for (int r = 0; r < 4; ++r) {
                float mn = fmaxf(m_i[r], mt[r]);
                alpha[r] = __expf(m_i[r] - mn);
                m_i[r] = mn;
            }
            #pragma unroll
            for (int nj = 0; nj < 4; ++nj)
                #pragma unroll
                for (int r = 0; r < 4; ++r) {
                    float p = __expf(acc_s[nj][r] - m_i[r]);
                    rs[r] += p;
                    Pw[(q4 * 4 + r) * 88 + nj * 16 + c] = (bf16_t)p;
                }
            #pragma unroll
            for (int r = 0; r < 4; ++r)
                l_i[r] = alpha[r] * l_i[r] + rowsum16(rs[r]);
            #pragma unroll
            for (int nj = 0; nj < 8; ++nj)
                #pragma unroll
                for (int r = 0; r < 4; ++r)
                    acc_o[nj][r] *= alpha[r];
        }

        // P store -> read is same-wave: lgkm wait only, no barrier
        LGKM0();
        __builtin_amdgcn_sched_barrier(0);

        // ---- O += P V : A = P [m][p], B = Vt [e][p] ----
        __builtin_amdgcn_s_setprio(1);
        #pragma unroll
        for (int ks = 0; ks < 2; ++ks) {
            bf16x8 ap = *(const bf16x8*)&Pw[c * 88 + ks * 32 + q4 * 8];
            #pragma unroll
            for (int nj = 0; nj < 8; ++nj) {
                int row = nj * 16 + c;
                bf16x8 bvv = *(const bf16x8*)&Vt[cur][row * 64 + (((ks * 4 + q4) ^ (c & 7)) * 8)];
                acc_o[nj] = __builtin_amdgcn_mfma_f32_16x16x32_bf16(
                    ap, bvv, acc_o[nj], 0, 0, 0);
            }
        }
        __builtin_amdgcn_s_setprio(0);
        BAR();             // all reads of buf[cur] done before next overwrite
    }
    VMW(0);                // drain tail junk stages before LDS goes away

    float inv[4];
    #pragma unroll
    for (int r = 0; r < 4; ++r) inv[r] = 1.0f / l_i[r];
    #pragma unroll
    for (int nj = 0; nj < 8; ++nj)
        #pragma unroll
        for (int r = 0; r < 4; ++r)
            O[(long long)(bm + w * 16 + q4 * 4 + r) * D + hE + nj * 16 + c] =
                (bf16_t)(acc_o[nj][r] * inv[r]);
    #undef FA_STAGE
}

// ---------------- small utility kernels ----------------
__global__ __launch_bounds__(256)
void cast4_bf16(const float* __restrict__ s0, const float* __restrict__ s1,
                const float* __restrict__ s2, const float* __restrict__ s3,
                bf16_t* __restrict__ d0, long long seg, long long n)
{
    const float* src = (blockIdx.y == 0) ? s0 : (blockIdx.y == 1) ? s1
                     : (blockIdx.y == 2) ? s2 : s3;
    bf16_t* dst = d0 + (long long)blockIdx.y * seg;
    long long i = ((long long)blockIdx.x * 256 + threadIdx.x) * 4;
    if (i >= n) return;
    float4 v = *(const float4*)(src + i);
    union { bf16_t b[4]; unsigned long long u; } o;
    o.b[0] = (bf16_t)v.x; o.b[1] = (bf16_t)v.y;
    o.b[2] = (bf16_t)v.z; o.b[3] = (bf16_t)v.w;
    *(unsigned long long*)(dst + i) = o.u;
}

__global__ __launch_bounds__(256)
void transpose_to_bf16(const float* __restrict__ in, bf16_t* __restrict__ out,
                       int rows, int cols)
{
    __shared__ bf16_t tile[32][33];
    const int r0 = blockIdx.y * 32, c0 = blockIdx.x * 32;
    const int tx = threadIdx.x & 31, ty = threadIdx.x >> 5;
    #pragma unroll
    for (int i = 0; i < 4; ++i) {
        int r = ty + i * 8;
        tile[r][tx] = (bf16_t)in[(long long)(r0 + r) * cols + c0 + tx];
    }
    __syncthreads();
    #pragma unroll
    for (int i = 0; i < 4; ++i) {
        int r = ty + i * 8;
        out[(long long)(c0 + r) * rows + r0 + tx] = tile[tx][r];
    }
}

__global__ __launch_bounds__(256)
void reduce4_f32(const float* __restrict__ p, float* __restrict__ out,
                 long long n)
{
    long long i = ((long long)blockIdx.x * 256 + threadIdx.x) * 4;
    if (i >= n) return;
    float4 a = *(const float4*)(p + i);
    float4 b = *(const float4*)(p + n + i);
    float4 c = *(const float4*)(p + 2 * n + i);
    float4 d = *(const float4*)(p + 3 * n + i);
    float4 o;
    o.x = a.x + b.x + c.x + d.x;
    o.y = a.y + b.y + c.y + d.y;
    o.z = a.z + b.z + c.z + d.z;
    o.w = a.w + b.w + c.w + d.w;
    *(float4*)(out + i) = o;
}

__global__ __launch_bounds__(256)
void reduce2_bf16(const float* __restrict__ p, bf16_t* __restrict__ out,
                  long long n)
{
    long long i = ((long long)blockIdx.x * 256 + threadIdx.x) * 4;
    if (i >= n) return;
    float4 a = *(const float4*)(p + i);
    float4 b = *(const float4*)(p + n + i);
    union { bf16_t b[4]; unsigned long long u; } o;
    o.b[0] = (bf16_t)(a.x + b.x);
    o.b[1] = (bf16_t)(a.y + b.y);
    o.b[2] = (bf16_t)(a.z + b.z);
    o.b[3] = (bf16_t)(a.w + b.w);
    *(unsigned long long*)(out + i) = o.u;
}

extern "C" void kernel_launch(void* const* d_in, const int* in_sizes, int n_in,
                              void* d_out, int out_size, void* d_ws, size_t ws_size,
                              hipStream_t stream)
{
    const float* I    = (const float*)d_in[0];
    const float* WV   = (const float*)d_in[1];
    const float* WK   = (const float*)d_in[2];
    const float* WQ   = (const float*)d_in[3];
    const float* WZ   = (const float*)d_in[4];
    const float* WFFA = (const float*)d_in[5];
    const float* WFFB = (const float*)d_in[6];
    float* out = (float*)d_out;                  // [M, D] fp32

    const int M = 2048, D = 2048, C = 8192;
    const long long MD = (long long)M * D;
    const size_t MiB = 1024 * 1024;

    char* base = (char*)d_ws;
    bf16_t* bI     = (bf16_t*)(base + 0 * MiB);
    bf16_t* bWQ    = (bf16_t*)(base + 8 * MiB);    // contiguous WQ,WK,WV (z-batch)
    bf16_t* bWK    = (bf16_t*)(base + 16 * MiB);
    bf16_t* bWV    = (bf16_t*)(base + 24 * MiB);
    bf16_t* bQ     = (bf16_t*)(base + 32 * MiB);   // contiguous Q,K (z-batch out)
    bf16_t* bK     = (bf16_t*)(base + 40 * MiB);
    bf16_t* bVT    = (bf16_t*)(base + 48 * MiB);   // [D, M] via ct_z epilogue
    bf16_t* bAV    = (bf16_t*)(base + 56 * MiB);
    bf16_t* bZ     = (bf16_t*)(base + 64 * MiB);
    bf16_t* bWZT   = (bf16_t*)(base + 72 * MiB);
    bf16_t* bWFFAT = (bf16_t*)(base + 80 * MiB);   // [C, D]
    bf16_t* bWFFBT = (bf16_t*)(base + 112 * MiB);  // [D, C]
    bf16_t* bFFA   = (bf16_t*)(base + 0 * MiB);    // [M, C] bf16 (bI..bWV dead)
    float*  pZ     = (float*)(base + 0 * MiB);     // 2x [M,D] fp32 Z partials
    float*  pF     = (float*)(base + 32 * MiB);    // 4x [M,D] fp32 FFB partials

    const dim3 blk(256);
    const dim3 blk512(512);

    // ---- prep: casts + weight transposes ----
    cast4_bf16<<<dim3(MD / 1024, 4), blk, 0, stream>>>(I, WQ, WK, WV, bI, MD, MD);
    transpose_to_bf16<<<dim3(D / 32, D / 32), blk, 0, stream>>>(WZ,   bWZT,   D, D);
    transpose_to_bf16<<<dim3(C / 32, D / 32), blk, 0, stream>>>(WFFA, bWFFAT, D, C);
    transpose_to_bf16<<<dim3(D / 32, C / 32), blk, 0, stream>>>(WFFB, bWFFBT, C, D);

    // ---- QKV in one z=3 dispatch; V -> bVT transposed ----
    gemm256p_bt<bf16_t><<<dim3(8, 8, 3), blk512, 0, stream>>>(
        bI, bWQ, bQ, D, D, D, D, 0, MD, MD, /*ct_z=*/2, bVT, M);

    // ---- flash attention: Q,K,VT -> AV ----
    flash_attn<<<dim3(M / 64, 16), blk, 0, stream>>>(bQ, bK, bVT, bAV, M, D);

    // ---- Z = AV x WZ^T, split-K=2 -> fp32 partials + reduce to bf16 ----
    gemm256p_bt<float><<<dim3(8, 8, 2), blk512, 0, stream>>>(
        bAV, bWZT, pZ, 1024, D, D, D, 1024, 1024, MD, -1, nullptr, 0);
    reduce2_bf16<<<dim3((int)(MD / 1024)), blk, 0, stream>>>(pZ, bZ, MD);

    // ---- FFA = Z x WFFA^T ----
    gemm256p_bt<bf16_t><<<dim3(32, 8, 1), blk512, 0, stream>>>(
        bZ, bWFFAT, bFFA, D, D, D, C, 0, 0, 0, -1, nullptr, 0);

    // ---- FFB = FFA x WFFB^T, split-K=4 -> fp32 partials (plain stores) ----
    gemm256p_bt<float><<<dim3(8, 8, 4), blk512, 0, stream>>>(
        bFFA, bWFFBT, pF, 2048, C, C, D, 2048, 2048, MD, -1, nullptr, 0);

    // ---- out = sum of 4 partials ----
    reduce4_f32<<<dim3((int)(MD / 1024)), blk, 0, stream>>>(pF, out, MD);
}